// Round 6
// baseline (733.112 us; speedup 1.0000x reference)
//
#include <hip/hip_runtime.h>
#include <hip/hip_bf16.h>

#define T_TOK 4096
#define D_DIM 1024
#define E_NUM 8
#define F_DIM 4096
#define NPAIR 8192

#define BM 128
#define BN 128
#define BK 64

typedef float f32x4 __attribute__((ext_vector_type(4)));
typedef __bf16 bf16x8 __attribute__((ext_vector_type(8)));
typedef unsigned short u16x8 __attribute__((ext_vector_type(8)));
typedef unsigned short u16x4 __attribute__((ext_vector_type(4)));

__device__ __forceinline__ unsigned short f2bf(float f) {
    unsigned int u = __float_as_uint(f);
    u += 0x7fffu + ((u >> 16) & 1u);
    return (unsigned short)(u >> 16);
}

typedef const __attribute__((address_space(1))) void GV;
typedef __attribute__((address_space(3))) void LV;

__device__ __forceinline__ void load_lds16(const void* g, void* l) {
    __builtin_amdgcn_global_load_lds((GV*)g, (LV*)l, 16, 0, 0);
}

// Swizzled LDS fragment read: logical (row, colShort cs) lives at
// byte = row*128 + ((cs*2) ^ ((row&7)<<4)). Writer: gload_lds writes linearly;
// the per-lane GLOBAL source column carries the matching permutation.
__device__ __forceinline__ bf16x8 lds_frag(const unsigned short* S, int row, int cs) {
    int byte = row * (BK * 2) + ((cs * 2) ^ ((row & 7) << 4));
    return *(const bf16x8*)((const char*)S + byte);
}

// ---------------- Router + x->bf16 convert: one wave per token ----------------
__global__ __launch_bounds__(256) void router_convert_kernel(
    const float* __restrict__ x, const float* __restrict__ noise,
    const float* __restrict__ Wg, const float* __restrict__ bg,
    const float* __restrict__ Wn, const float* __restrict__ bn,
    float* __restrict__ out_noisy, float* __restrict__ out_gate,
    int* __restrict__ tk_idx, float* __restrict__ tk_w,
    unsigned short* __restrict__ xb)
{
    int lane = threadIdx.x & 63;
    int t = blockIdx.x * 4 + (threadIdx.x >> 6);
    const float* xr = x + (size_t)t * D_DIM;
    unsigned short* xbr = xb + (size_t)t * D_DIM;

    // convert this token's row to bf16 (fused with router: one x pass)
    #pragma unroll
    for (int r = 0; r < 4; ++r) {
        int d = r * 256 + lane * 4;
        float4 v = *(const float4*)(xr + d);
        u16x4 o;
        o[0] = f2bf(v.x); o[1] = f2bf(v.y); o[2] = f2bf(v.z); o[3] = f2bf(v.w);
        *(u16x4*)(xbr + d) = o;
    }

    float ag[E_NUM] = {}, an[E_NUM] = {};
    for (int it = 0; it < D_DIM / 64; ++it) {
        int d = it * 64 + lane;
        float xv = xr[d];
        float4 g0 = *(const float4*)(Wg + (size_t)d * E_NUM);
        float4 g1 = *(const float4*)(Wg + (size_t)d * E_NUM + 4);
        float4 m0 = *(const float4*)(Wn + (size_t)d * E_NUM);
        float4 m1 = *(const float4*)(Wn + (size_t)d * E_NUM + 4);
        ag[0] += xv * g0.x; ag[1] += xv * g0.y; ag[2] += xv * g0.z; ag[3] += xv * g0.w;
        ag[4] += xv * g1.x; ag[5] += xv * g1.y; ag[6] += xv * g1.z; ag[7] += xv * g1.w;
        an[0] += xv * m0.x; an[1] += xv * m0.y; an[2] += xv * m0.z; an[3] += xv * m0.w;
        an[4] += xv * m1.x; an[5] += xv * m1.y; an[6] += xv * m1.z; an[7] += xv * m1.w;
    }
    #pragma unroll
    for (int off = 32; off > 0; off >>= 1) {
        #pragma unroll
        for (int e = 0; e < E_NUM; ++e) {
            ag[e] += __shfl_xor(ag[e], off);
            an[e] += __shfl_xor(an[e], off);
        }
    }
    if (lane == 0) {
        float nz[E_NUM];
        #pragma unroll
        for (int e = 0; e < E_NUM; ++e) {
            float g = ag[e] + bg[e];
            float nn = an[e] + bn[e];
            float sp = fmaxf(nn, 0.f) + log1pf(expf(-fabsf(nn)));
            float z = g + noise[(size_t)t * E_NUM + e] * sp;
            out_gate[(size_t)t * E_NUM + e] = g;
            out_noisy[(size_t)t * E_NUM + e] = z;
            nz[e] = z;
        }
        int e0 = 0;
        #pragma unroll
        for (int e = 1; e < E_NUM; ++e) if (nz[e] > nz[e0]) e0 = e;
        int e1 = (e0 == 0) ? 1 : 0;
        #pragma unroll
        for (int e = 0; e < E_NUM; ++e) if (e != e0 && nz[e] > nz[e1]) e1 = e;
        float b = expf(nz[e1] - nz[e0]);  // <= 1
        float w0 = 1.f / (1.f + b);
        float w1 = b / (1.f + b);
        tk_idx[t * 2] = e0;  tk_idx[t * 2 + 1] = e1;
        tk_w[t * 2] = w0;    tk_w[t * 2 + 1] = w1;
    }
}

// ---------------- Deterministic group-by-expert (1 block) ----------------
__global__ __launch_bounds__(256) void scan_scatter_kernel(
    const int* __restrict__ tk_idx,
    int* __restrict__ perm, int* __restrict__ meta)
{
    __shared__ int cnt[256][E_NUM];
    __shared__ int soff[E_NUM];
    int tid = threadIdx.x;
    const int PPT = NPAIR / 256;
    int p0 = tid * PPT;

    int c[E_NUM] = {};
    for (int i = 0; i < PPT; ++i) c[tk_idx[p0 + i]]++;
    #pragma unroll
    for (int e = 0; e < E_NUM; ++e) cnt[tid][e] = c[e];
    __syncthreads();

    if (tid < E_NUM) {
        int s = 0;
        for (int j = 0; j < 256; ++j) { int v = cnt[j][tid]; cnt[j][tid] = s; s += v; }
        soff[tid] = s;
    }
    __syncthreads();

    if (tid == 0) {
        int off = 0, nt = 0;
        for (int e = 0; e < E_NUM; ++e) {
            int ce = soff[e];
            meta[1 + e] = off;
            meta[9 + e] = ce;
            for (int j = 0; j < ce; j += BM) {
                meta[32 + nt]  = e;
                meta[160 + nt] = off + j;
                meta[288 + nt] = off + ce;
                nt++;
            }
            off += ce;
        }
        meta[0] = nt;
    }
    __syncthreads();
    if (tid < E_NUM) soff[tid] = meta[1 + tid];
    __syncthreads();

    int pos[E_NUM];
    #pragma unroll
    for (int e = 0; e < E_NUM; ++e) pos[e] = soff[e] + cnt[tid][e];
    for (int i = 0; i < PPT; ++i) {
        int e = tk_idx[p0 + i];
        perm[pos[e]++] = p0 + i;
    }
}

// ---------------- W [E][R][C] f32 -> WT [E][C][R] bf16, 64x64 tiles ----------------
__global__ __launch_bounds__(256) void transpose_kernel(
    const float* __restrict__ W, unsigned short* __restrict__ WT, int R, int C)
{
    __shared__ float tile[64][65];
    int e = blockIdx.z;
    int c0 = blockIdx.x * 64, r0 = blockIdx.y * 64;
    int tx = threadIdx.x & 15, ty = threadIdx.x >> 4;   // load: 16 thr x float4 = one 64-wide row
    const float* src = W + (size_t)e * R * C;
    #pragma unroll
    for (int j = 0; j < 4; ++j) {
        int r = ty + 16 * j;
        float4 v = *(const float4*)(src + (size_t)(r0 + r) * C + c0 + tx * 4);
        *(float4*)&tile[r][tx * 4] = v;
    }
    __syncthreads();
    unsigned short* dst = WT + (size_t)e * C * R;
    int sx = threadIdx.x & 7, sy = threadIdx.x >> 3;    // store: 8 thr x 16B = one 64-short row
    #pragma unroll
    for (int j = 0; j < 2; ++j) {
        int c = sy + 32 * j;
        u16x8 o;
        #pragma unroll
        for (int k = 0; k < 8; ++k) o[k] = f2bf(tile[sx * 8 + k][c]);
        *(u16x8*)(dst + (size_t)(c0 + c) * R + r0 + sx * 8) = o;
    }
}

// ---- shared GEMM compute over one staged K-tile (per-wave 64x64 C) ----
#define GEMM_COMPUTE(Abuf, Bbuf) do {                                                      \
    _Pragma("unroll")                                                                      \
    for (int kk = 0; kk < BK; kk += 32) {                                                  \
        bf16x8 af[4], bf[4];                                                               \
        _Pragma("unroll")                                                                  \
        for (int m_ = 0; m_ < 4; ++m_)                                                     \
            af[m_] = lds_frag((Abuf), wm + m_ * 16 + (lane & 15), kk + (lane >> 4) * 8);   \
        _Pragma("unroll")                                                                  \
        for (int n_ = 0; n_ < 4; ++n_)                                                     \
            bf[n_] = lds_frag((Bbuf), wn + n_ * 16 + (lane & 15), kk + (lane >> 4) * 8);   \
        _Pragma("unroll")                                                                  \
        for (int m_ = 0; m_ < 4; ++m_)                                                     \
            _Pragma("unroll")                                                              \
            for (int n_ = 0; n_ < 4; ++n_)                                                 \
                acc[m_][n_] = __builtin_amdgcn_mfma_f32_16x16x32_bf16(af[m_], bf[n_],      \
                                                                      acc[m_][n_], 0, 0, 0); \
    }                                                                                      \
} while (0)

// ---------------- FC1: h = gelu(x @ W1 + b1), 4-buffer depth-3 pipeline ----------------
__global__ __launch_bounds__(256, 1) void fc1_kernel(
    const unsigned short* __restrict__ xb,    // [T][D] bf16
    const unsigned short* __restrict__ W1T,   // [E][F][D] bf16
    const float* __restrict__ b1,             // [E][F]
    const int* __restrict__ perm,
    const int* __restrict__ meta,
    unsigned short* __restrict__ h)           // [NPAIR][F] bf16
{
    const int nwg = 71 * (F_DIM / BN);        // 2272, % 8 == 0
    const int cpx = nwg >> 3;
    int bid = blockIdx.x;
    int wg = (bid & 7) * cpx + (bid >> 3);
    int tile = wg >> 5;
    int n0 = (wg & 31) * BN;
    if (tile >= meta[0]) return;
    int e    = meta[32 + tile];
    int rs   = meta[160 + tile];
    int rend = meta[288 + tile];

    __shared__ __align__(16) unsigned short As[4][BM * BK];   // 4 x 16 KB
    __shared__ __align__(16) unsigned short Bs[4][BN * BK];   // 4 x 16 KB

    int tid = threadIdx.x, lane = tid & 63, wv = tid >> 6;
    int wm = (wv >> 1) * 64, wn = (wv & 1) * 64;
    int csw = ((tid & 7) ^ ((tid >> 3) & 7)) * 8;  // pre-swizzled global col

    const unsigned short* asrc[4];
    #pragma unroll
    for (int i = 0; i < 4; ++i) {
        int q = tid + i * 256;
        int pos = rs + (q >> 3); if (pos >= NPAIR) pos = NPAIR - 1;
        int t = perm[pos] >> 1;
        asrc[i] = xb + (size_t)t * D_DIM + csw;
    }
    const unsigned short* bbase = W1T + ((size_t)e * F_DIM + n0 + wv * 32 + (lane >> 3)) * D_DIM + csw;

    f32x4 acc[4][4] = {};

#define STAGE1(k0, b) do {                                                          \
    _Pragma("unroll")                                                               \
    for (int i_ = 0; i_ < 4; ++i_)                                                  \
        load_lds16(asrc[i_] + (k0), &As[b][(wv * 64 + i_ * 256) * 8]);              \
    _Pragma("unroll")                                                               \
    for (int j_ = 0; j_ < 4; ++j_)                                                  \
        load_lds16(bbase + (size_t)(j_ * 8) * D_DIM + (k0), &Bs[b][(wv * 32 + j_ * 8) * BK]); \
} while (0)

    const int NT = D_DIM / BK;   // 16
    STAGE1(0, 0); STAGE1(BK, 1); STAGE1(2 * BK, 2);   // prologue: 3 tiles in flight
    for (int t = 0; t < NT; ++t) {
        int cb = t & 3;
        if (t + 3 < NT) {
            STAGE1((t + 3) * BK, (t + 3) & 3);        // dest buf last read at iter t-1: safe
            asm volatile("s_waitcnt vmcnt(24)" ::: "memory");   // tile t landed; 3 in flight
        } else if (t + 3 == NT) {
            asm volatile("s_waitcnt vmcnt(16)" ::: "memory");
        } else if (t + 2 == NT) {
            asm volatile("s_waitcnt vmcnt(8)" ::: "memory");
        } else {
            asm volatile("s_waitcnt vmcnt(0)" ::: "memory");
        }
        __builtin_amdgcn_s_barrier();
        GEMM_COMPUTE(As[cb], Bs[cb]);
        asm volatile("s_waitcnt lgkmcnt(0)" ::: "memory");
        __builtin_amdgcn_s_barrier();   // all waves done reading buf[cb]
    }
#undef STAGE1

    #pragma unroll
    for (int m = 0; m < 4; ++m) {
        #pragma unroll
        for (int j = 0; j < 4; ++j) {
            int r = wm + m * 16 + (lane >> 4) * 4 + j;
            int pos = rs + r;
            if (pos >= rend) continue;
            #pragma unroll
            for (int n = 0; n < 4; ++n) {
                int col = n0 + wn + n * 16 + (lane & 15);
                float v = acc[m][n][j] + b1[e * F_DIM + col];
                v = 0.5f * v * (1.f + erff(v * 0.70710678118654752f));  // exact GELU
                h[(size_t)pos * F_DIM + col] = f2bf(v);
            }
        }
    }
}

// ---------------- FC2: out += w * (h @ W2 + b2), splitK=2, depth-3 pipeline ----------------
__global__ __launch_bounds__(256, 1) void fc2_kernel(
    const unsigned short* __restrict__ h,     // [NPAIR][F] bf16 (grouped rows contiguous)
    const unsigned short* __restrict__ W2T,   // [E][D][F] bf16
    const float* __restrict__ b2,             // [E][D]
    const int* __restrict__ perm,
    const float* __restrict__ tk_w,
    const int* __restrict__ meta,
    float* __restrict__ out)                  // [T][D] fp32 (zeroed)
{
    const int nwg = 71 * (D_DIM / BN) * 2;    // 1136, % 8 == 0
    const int cpx = nwg >> 3;
    int bid = blockIdx.x;
    int wg = (bid & 7) * cpx + (bid >> 3);
    int tile = wg >> 4;
    int rem  = wg & 15;
    int n0 = (rem >> 1) * BN;
    int ks = rem & 1;
    if (tile >= meta[0]) return;
    int e    = meta[32 + tile];
    int rs   = meta[160 + tile];
    int rend = meta[288 + tile];
    int kbeg = ks * (F_DIM / 2);

    __shared__ __align__(16) unsigned short As[4][BM * BK];
    __shared__ __align__(16) unsigned short Bs[4][BN * BK];

    int tid = threadIdx.x, lane = tid & 63, wv = tid >> 6;
    int wm = (wv >> 1) * 64, wn = (wv & 1) * 64;
    int csw = ((tid & 7) ^ ((tid >> 3) & 7)) * 8;

    const unsigned short* asrc[4];
    #pragma unroll
    for (int i = 0; i < 4; ++i) {
        int q = tid + i * 256;
        int pos = rs + (q >> 3); if (pos >= NPAIR) pos = NPAIR - 1;
        asrc[i] = h + (size_t)pos * F_DIM + kbeg + csw;
    }
    const unsigned short* bbase = W2T + ((size_t)e * D_DIM + n0 + wv * 32 + (lane >> 3)) * F_DIM
                                + kbeg + csw;

    f32x4 acc[4][4] = {};

#define STAGE2(k0, b) do {                                                          \
    _Pragma("unroll")                                                               \
    for (int i_ = 0; i_ < 4; ++i_)                                                  \
        load_lds16(asrc[i_] + (k0), &As[b][(wv * 64 + i_ * 256) * 8]);              \
    _Pragma("unroll")                                                               \
    for (int j_ = 0; j_ < 4; ++j_)                                                  \
        load_lds16(bbase + (size_t)(j_ * 8) * F_DIM + (k0), &Bs[b][(wv * 32 + j_ * 8) * BK]); \
} while (0)

    const int NT = (F_DIM / 2) / BK;   // 32
    STAGE2(0, 0); STAGE2(BK, 1); STAGE2(2 * BK, 2);
    for (int t = 0; t < NT; ++t) {
        int cb = t & 3;
        if (t + 3 < NT) {
            STAGE2((t + 3) * BK, (t + 3) & 3);
            asm volatile("s_waitcnt vmcnt(24)" ::: "memory");
        } else if (t + 3 == NT) {
            asm volatile("s_waitcnt vmcnt(16)" ::: "memory");
        } else if (t + 2 == NT) {
            asm volatile("s_waitcnt vmcnt(8)" ::: "memory");
        } else {
            asm volatile("s_waitcnt vmcnt(0)" ::: "memory");
        }
        __builtin_amdgcn_s_barrier();
        GEMM_COMPUTE(As[cb], Bs[cb]);
        asm volatile("s_waitcnt lgkmcnt(0)" ::: "memory");
        __builtin_amdgcn_s_barrier();
    }
#undef STAGE2

    #pragma unroll
    for (int m = 0; m < 4; ++m) {
        #pragma unroll
        for (int j = 0; j < 4; ++j) {
            int r = wm + m * 16 + (lane >> 4) * 4 + j;
            int pos = rs + r;
            if (pos >= rend) continue;
            int pr = perm[pos];
            int t = pr >> 1;
            float w = tk_w[pr];
            #pragma unroll
            for (int n = 0; n < 4; ++n) {
                int col = n0 + wn + n * 16 + (lane & 15);
                float base = (ks == 0) ? b2[e * D_DIM + col] : 0.f;
                float v = (acc[m][n][j] + base) * w;
                atomicAdd(&out[(size_t)t * D_DIM + col], v);
            }
        }
    }
}

extern "C" void kernel_launch(void* const* d_in, const int* in_sizes, int n_in,
                              void* d_out, int out_size, void* d_ws, size_t ws_size,
                              hipStream_t stream)
{
    const float* x     = (const float*)d_in[0];
    const float* noise = (const float*)d_in[1];
    const float* Wg    = (const float*)d_in[2];
    const float* bg    = (const float*)d_in[3];
    const float* Wn    = (const float*)d_in[4];
    const float* bn    = (const float*)d_in[5];
    const float* W1    = (const float*)d_in[6];
    const float* b1    = (const float*)d_in[7];
    const float* W2    = (const float*)d_in[8];
    const float* b2    = (const float*)d_in[9];

    float* out       = (float*)d_out;
    float* out_noisy = out + (size_t)T_TOK * D_DIM;
    float* out_gate  = out_noisy + (size_t)T_TOK * E_NUM;

    char* ws = (char*)d_ws;
    int*   tk_idx = (int*)ws;
    float* tk_w   = (float*)(ws + 32768);
    int*   perm   = (int*)(ws + 65536);
    int*   meta   = (int*)(ws + 98304);
    size_t off = 131072;
    unsigned short* xb   = (unsigned short*)(ws + off); off += (size_t)T_TOK * D_DIM * 2;
    unsigned short* W1T  = (unsigned short*)(ws + off); off += (size_t)E_NUM * F_DIM * D_DIM * 2;
    unsigned short* W2T  = (unsigned short*)(ws + off); off += (size_t)E_NUM * D_DIM * F_DIM * 2;
    unsigned short* hbuf = (unsigned short*)(ws + off); off += (size_t)NPAIR * F_DIM * 2;

    hipMemsetAsync(d_out, 0, (size_t)out_size * sizeof(float), stream);

    router_convert_kernel<<<T_TOK / 4, 256, 0, stream>>>(x, noise, Wg, bg, Wn, bn,
                                                         out_noisy, out_gate, tk_idx, tk_w, xb);
    scan_scatter_kernel<<<1, 256, 0, stream>>>(tk_idx, perm, meta);
    // W2T early (its L3 footprint precedes fc1's streaming); W1T right before fc1.
    transpose_kernel<<<dim3(D_DIM / 64, F_DIM / 64, E_NUM), 256, 0, stream>>>(W2, W2T, F_DIM, D_DIM);
    transpose_kernel<<<dim3(F_DIM / 64, D_DIM / 64, E_NUM), 256, 0, stream>>>(W1, W1T, D_DIM, F_DIM);

    fc1_kernel<<<71 * (F_DIM / BN), 256, 0, stream>>>(xb, W1T, b1, perm, meta, hbuf);
    fc2_kernel<<<71 * (D_DIM / BN) * 2, 256, 0, stream>>>(hbuf, W2T, b2, perm, tk_w, meta, out);
}

// Round 7
// 671.253 us; speedup vs baseline: 1.0922x; 1.0922x over previous
//
#include <hip/hip_runtime.h>
#include <hip/hip_bf16.h>

#define T_TOK 4096
#define D_DIM 1024
#define E_NUM 8
#define F_DIM 4096
#define NPAIR 8192

#define BM 256
#define BN 256
#define BK 64
#define NTMAX 40   // max tiles: 8192/256 + 8 experts of slack

typedef float f32x4 __attribute__((ext_vector_type(4)));
typedef __bf16 bf16x8 __attribute__((ext_vector_type(8)));
typedef unsigned short u16x8 __attribute__((ext_vector_type(8)));
typedef unsigned short u16x4 __attribute__((ext_vector_type(4)));

__device__ __forceinline__ unsigned short f2bf(float f) {
    unsigned int u = __float_as_uint(f);
    u += 0x7fffu + ((u >> 16) & 1u);
    return (unsigned short)(u >> 16);
}

typedef const __attribute__((address_space(1))) void GV;
typedef __attribute__((address_space(3))) void LV;

__device__ __forceinline__ void load_lds16(const void* g, void* l) {
    __builtin_amdgcn_global_load_lds((GV*)g, (LV*)l, 16, 0, 0);
}

// Swizzled LDS fragment read: logical (row, colShort cs) lives at
// byte = row*128 + ((cs*2) ^ ((row&7)<<4)). Writer: gload_lds writes linearly;
// the per-lane GLOBAL source column carries the matching permutation.
__device__ __forceinline__ bf16x8 lds_frag(const unsigned short* S, int row, int cs) {
    int byte = row * (BK * 2) + ((cs * 2) ^ ((row & 7) << 4));
    return *(const bf16x8*)((const char*)S + byte);
}

// ---------------- Router + x->bf16 convert: one wave per token ----------------
__global__ __launch_bounds__(256) void router_convert_kernel(
    const float* __restrict__ x, const float* __restrict__ noise,
    const float* __restrict__ Wg, const float* __restrict__ bg,
    const float* __restrict__ Wn, const float* __restrict__ bn,
    float* __restrict__ out_noisy, float* __restrict__ out_gate,
    int* __restrict__ tk_idx, float* __restrict__ tk_w,
    unsigned short* __restrict__ xb)
{
    int lane = threadIdx.x & 63;
    int t = blockIdx.x * 4 + (threadIdx.x >> 6);
    const float* xr = x + (size_t)t * D_DIM;
    unsigned short* xbr = xb + (size_t)t * D_DIM;

    #pragma unroll
    for (int r = 0; r < 4; ++r) {
        int d = r * 256 + lane * 4;
        float4 v = *(const float4*)(xr + d);
        u16x4 o;
        o[0] = f2bf(v.x); o[1] = f2bf(v.y); o[2] = f2bf(v.z); o[3] = f2bf(v.w);
        *(u16x4*)(xbr + d) = o;
    }

    float ag[E_NUM] = {}, an[E_NUM] = {};
    for (int it = 0; it < D_DIM / 64; ++it) {
        int d = it * 64 + lane;
        float xv = xr[d];
        float4 g0 = *(const float4*)(Wg + (size_t)d * E_NUM);
        float4 g1 = *(const float4*)(Wg + (size_t)d * E_NUM + 4);
        float4 m0 = *(const float4*)(Wn + (size_t)d * E_NUM);
        float4 m1 = *(const float4*)(Wn + (size_t)d * E_NUM + 4);
        ag[0] += xv * g0.x; ag[1] += xv * g0.y; ag[2] += xv * g0.z; ag[3] += xv * g0.w;
        ag[4] += xv * g1.x; ag[5] += xv * g1.y; ag[6] += xv * g1.z; ag[7] += xv * g1.w;
        an[0] += xv * m0.x; an[1] += xv * m0.y; an[2] += xv * m0.z; an[3] += xv * m0.w;
        an[4] += xv * m1.x; an[5] += xv * m1.y; an[6] += xv * m1.z; an[7] += xv * m1.w;
    }
    #pragma unroll
    for (int off = 32; off > 0; off >>= 1) {
        #pragma unroll
        for (int e = 0; e < E_NUM; ++e) {
            ag[e] += __shfl_xor(ag[e], off);
            an[e] += __shfl_xor(an[e], off);
        }
    }
    if (lane == 0) {
        float nz[E_NUM];
        #pragma unroll
        for (int e = 0; e < E_NUM; ++e) {
            float g = ag[e] + bg[e];
            float nn = an[e] + bn[e];
            float sp = fmaxf(nn, 0.f) + log1pf(expf(-fabsf(nn)));
            float z = g + noise[(size_t)t * E_NUM + e] * sp;
            out_gate[(size_t)t * E_NUM + e] = g;
            out_noisy[(size_t)t * E_NUM + e] = z;
            nz[e] = z;
        }
        int e0 = 0;
        #pragma unroll
        for (int e = 1; e < E_NUM; ++e) if (nz[e] > nz[e0]) e0 = e;
        int e1 = (e0 == 0) ? 1 : 0;
        #pragma unroll
        for (int e = 0; e < E_NUM; ++e) if (e != e0 && nz[e] > nz[e1]) e1 = e;
        float b = expf(nz[e1] - nz[e0]);  // <= 1
        float w0 = 1.f / (1.f + b);
        float w1 = b / (1.f + b);
        tk_idx[t * 2] = e0;  tk_idx[t * 2 + 1] = e1;
        tk_w[t * 2] = w0;    tk_w[t * 2 + 1] = w1;
    }
}

// ---------------- Deterministic group-by-expert (1 block) ----------------
__global__ __launch_bounds__(256) void scan_scatter_kernel(
    const int* __restrict__ tk_idx,
    int* __restrict__ perm, int* __restrict__ meta)
{
    __shared__ int cnt[256][E_NUM];
    __shared__ int soff[E_NUM];
    int tid = threadIdx.x;
    const int PPT = NPAIR / 256;
    int p0 = tid * PPT;

    int c[E_NUM] = {};
    for (int i = 0; i < PPT; ++i) c[tk_idx[p0 + i]]++;
    #pragma unroll
    for (int e = 0; e < E_NUM; ++e) cnt[tid][e] = c[e];
    __syncthreads();

    if (tid < E_NUM) {
        int s = 0;
        for (int j = 0; j < 256; ++j) { int v = cnt[j][tid]; cnt[j][tid] = s; s += v; }
        soff[tid] = s;
    }
    __syncthreads();

    if (tid == 0) {
        int off = 0, nt = 0;
        for (int e = 0; e < E_NUM; ++e) {
            int ce = soff[e];
            meta[1 + e] = off;
            meta[9 + e] = ce;
            for (int j = 0; j < ce; j += BM) {
                meta[32 + nt]  = e;
                meta[160 + nt] = off + j;
                meta[288 + nt] = off + ce;
                nt++;
            }
            off += ce;
        }
        meta[0] = nt;
    }
    __syncthreads();
    if (tid < E_NUM) soff[tid] = meta[1 + tid];
    __syncthreads();

    int pos[E_NUM];
    #pragma unroll
    for (int e = 0; e < E_NUM; ++e) pos[e] = soff[e] + cnt[tid][e];
    for (int i = 0; i < PPT; ++i) {
        int e = tk_idx[p0 + i];
        perm[pos[e]++] = p0 + i;
    }
}

// ---------------- W [E][R][C] f32 -> WT [E][C][R] bf16, 64x64 tiles ----------------
__global__ __launch_bounds__(256) void transpose_kernel(
    const float* __restrict__ W, unsigned short* __restrict__ WT, int R, int C)
{
    __shared__ float tile[64][65];
    int e = blockIdx.z;
    int c0 = blockIdx.x * 64, r0 = blockIdx.y * 64;
    int tx = threadIdx.x & 15, ty = threadIdx.x >> 4;
    const float* src = W + (size_t)e * R * C;
    #pragma unroll
    for (int j = 0; j < 4; ++j) {
        int r = ty + 16 * j;
        float4 v = *(const float4*)(src + (size_t)(r0 + r) * C + c0 + tx * 4);
        *(float4*)&tile[r][tx * 4] = v;
    }
    __syncthreads();
    unsigned short* dst = WT + (size_t)e * C * R;
    int sx = threadIdx.x & 7, sy = threadIdx.x >> 3;
    #pragma unroll
    for (int j = 0; j < 2; ++j) {
        int c = sy + 32 * j;
        u16x8 o;
        #pragma unroll
        for (int k = 0; k < 8; ++k) o[k] = f2bf(tile[sx * 8 + k][c]);
        *(u16x8*)(dst + (size_t)(c0 + c) * R + r0 + sx * 8) = o;
    }
}

// ---- per-wave 128x64 C compute over one staged K-tile (8 waves: 2M x 4N) ----
#define GEMM_COMPUTE(Abuf, Bbuf) do {                                                      \
    _Pragma("unroll")                                                                      \
    for (int kk = 0; kk < BK; kk += 32) {                                                  \
        bf16x8 af[8], bf[4];                                                               \
        _Pragma("unroll")                                                                  \
        for (int m_ = 0; m_ < 8; ++m_)                                                     \
            af[m_] = lds_frag((Abuf), wm + m_ * 16 + (lane & 15), kk + (lane >> 4) * 8);   \
        _Pragma("unroll")                                                                  \
        for (int n_ = 0; n_ < 4; ++n_)                                                     \
            bf[n_] = lds_frag((Bbuf), wn + n_ * 16 + (lane & 15), kk + (lane >> 4) * 8);   \
        _Pragma("unroll")                                                                  \
        for (int m_ = 0; m_ < 8; ++m_)                                                     \
            _Pragma("unroll")                                                              \
            for (int n_ = 0; n_ < 4; ++n_)                                                 \
                acc[m_][n_] = __builtin_amdgcn_mfma_f32_16x16x32_bf16(af[m_], bf[n_],      \
                                                                      acc[m_][n_], 0, 0, 0); \
    }                                                                                      \
} while (0)

// ---------------- FC1: h = gelu(x @ W1 + b1), 256x256, dbuf + counted vmcnt ----------------
__global__ __launch_bounds__(512, 1) void fc1_kernel(
    const unsigned short* __restrict__ xb,    // [T][D] bf16
    const unsigned short* __restrict__ W1T,   // [E][F][D] bf16
    const float* __restrict__ b1,             // [E][F]
    const int* __restrict__ perm,
    const int* __restrict__ meta,
    unsigned short* __restrict__ h)           // [NPAIR][F] bf16
{
    const int nwg = NTMAX * 16;               // 640, % 8 == 0
    int bid = blockIdx.x;
    int wg = (bid & 7) * (nwg >> 3) + (bid >> 3);
    int tile = wg >> 4;                       // tile-major: consecutive wg share A panel
    int n0 = (wg & 15) * BN;
    if (tile >= meta[0]) return;
    int e    = meta[32 + tile];
    int rs   = meta[160 + tile];
    int rend = meta[288 + tile];

    __shared__ __align__(16) unsigned short As[2][BM * BK];   // 2 x 32 KB
    __shared__ __align__(16) unsigned short Bs[2][BN * BK];   // 2 x 32 KB

    int tid = threadIdx.x, lane = tid & 63, wv = tid >> 6;    // 8 waves
    int wm = (wv >> 2) * 128, wn = (wv & 3) * 64;
    int csw = ((tid & 7) ^ ((tid >> 3) & 7)) * 8;  // pre-swizzled global col

    const unsigned short* asrc[4];
    const unsigned short* bsrc[4];
    #pragma unroll
    for (int i = 0; i < 4; ++i) {
        int q = tid + i * 512;
        int row = q >> 3;
        int pos = rs + row; if (pos >= NPAIR) pos = NPAIR - 1;
        int t = perm[pos] >> 1;
        asrc[i] = xb + (size_t)t * D_DIM + csw;
        bsrc[i] = W1T + ((size_t)e * F_DIM + n0 + row) * D_DIM + csw;
    }

    f32x4 acc[8][4] = {};

#define STAGE1(k0, b) do {                                                \
    _Pragma("unroll")                                                     \
    for (int i_ = 0; i_ < 4; ++i_)                                        \
        load_lds16(asrc[i_] + (k0), &As[b][(tid + i_ * 512) * 8]);        \
    _Pragma("unroll")                                                     \
    for (int i_ = 0; i_ < 4; ++i_)                                        \
        load_lds16(bsrc[i_] + (k0), &Bs[b][(tid + i_ * 512) * 8]);        \
} while (0)

    const int NT = D_DIM / BK;   // 16
    STAGE1(0, 0);
    for (int t = 0; t < NT; ++t) {
        int cb = t & 1;
        if (t + 1 < NT) {
            STAGE1((t + 1) * BK, cb ^ 1);
            asm volatile("s_waitcnt vmcnt(8)" ::: "memory");   // tile t landed; t+1 in flight
        } else {
            asm volatile("s_waitcnt vmcnt(0)" ::: "memory");
        }
        __builtin_amdgcn_s_barrier();
        __builtin_amdgcn_s_setprio(1);
        GEMM_COMPUTE(As[cb], Bs[cb]);
        __builtin_amdgcn_s_setprio(0);
        asm volatile("s_waitcnt lgkmcnt(0)" ::: "memory");
        __builtin_amdgcn_s_barrier();   // all waves done reading buf[cb] before overwrite
    }
#undef STAGE1

    #pragma unroll
    for (int m = 0; m < 8; ++m) {
        #pragma unroll
        for (int j = 0; j < 4; ++j) {
            int r = wm + m * 16 + (lane >> 4) * 4 + j;
            int pos = rs + r;
            if (pos >= rend) continue;
            #pragma unroll
            for (int n = 0; n < 4; ++n) {
                int col = n0 + wn + n * 16 + (lane & 15);
                float v = acc[m][n][j] + b1[e * F_DIM + col];
                v = 0.5f * v * (1.f + erff(v * 0.70710678118654752f));  // exact GELU
                h[(size_t)pos * F_DIM + col] = f2bf(v);
            }
        }
    }
}

// ---------------- FC2: out += w * (h @ W2 + b2), 256x256, splitK=4 ----------------
__global__ __launch_bounds__(512, 1) void fc2_kernel(
    const unsigned short* __restrict__ h,     // [NPAIR][F] bf16 (grouped rows contiguous)
    const unsigned short* __restrict__ W2T,   // [E][D][F] bf16
    const float* __restrict__ b2,             // [E][D]
    const int* __restrict__ perm,
    const float* __restrict__ tk_w,
    const int* __restrict__ meta,
    float* __restrict__ out)                  // [T][D] fp32 (zeroed)
{
    const int nwg = NTMAX * 16;               // 40 tiles x 4 n0 x 4 ks = 640
    int bid = blockIdx.x;
    int wg = (bid & 7) * (nwg >> 3) + (bid >> 3);
    int tile = wg >> 4;
    int rem  = wg & 15;
    int n0 = (rem >> 2) * BN;                 // 4 D-blocks
    int ks = rem & 3;                         // 4 K-splits
    if (tile >= meta[0]) return;
    int e    = meta[32 + tile];
    int rs   = meta[160 + tile];
    int rend = meta[288 + tile];
    int kbeg = ks * (F_DIM / 4);

    __shared__ __align__(16) unsigned short As[2][BM * BK];
    __shared__ __align__(16) unsigned short Bs[2][BN * BK];

    int tid = threadIdx.x, lane = tid & 63, wv = tid >> 6;
    int wm = (wv >> 2) * 128, wn = (wv & 3) * 64;
    int csw = ((tid & 7) ^ ((tid >> 3) & 7)) * 8;

    const unsigned short* asrc[4];
    const unsigned short* bsrc[4];
    #pragma unroll
    for (int i = 0; i < 4; ++i) {
        int q = tid + i * 512;
        int row = q >> 3;
        int pos = rs + row; if (pos >= NPAIR) pos = NPAIR - 1;
        asrc[i] = h + (size_t)pos * F_DIM + kbeg + csw;
        bsrc[i] = W2T + ((size_t)e * D_DIM + n0 + row) * F_DIM + kbeg + csw;
    }

    f32x4 acc[8][4] = {};

#define STAGE2(k0, b) do {                                                \
    _Pragma("unroll")                                                     \
    for (int i_ = 0; i_ < 4; ++i_)                                        \
        load_lds16(asrc[i_] + (k0), &As[b][(tid + i_ * 512) * 8]);        \
    _Pragma("unroll")                                                     \
    for (int i_ = 0; i_ < 4; ++i_)                                        \
        load_lds16(bsrc[i_] + (k0), &Bs[b][(tid + i_ * 512) * 8]);        \
} while (0)

    const int NT = (F_DIM / 4) / BK;   // 16
    STAGE2(0, 0);
    for (int t = 0; t < NT; ++t) {
        int cb = t & 1;
        if (t + 1 < NT) {
            STAGE2((t + 1) * BK, cb ^ 1);
            asm volatile("s_waitcnt vmcnt(8)" ::: "memory");
        } else {
            asm volatile("s_waitcnt vmcnt(0)" ::: "memory");
        }
        __builtin_amdgcn_s_barrier();
        __builtin_amdgcn_s_setprio(1);
        GEMM_COMPUTE(As[cb], Bs[cb]);
        __builtin_amdgcn_s_setprio(0);
        asm volatile("s_waitcnt lgkmcnt(0)" ::: "memory");
        __builtin_amdgcn_s_barrier();
    }
#undef STAGE2

    #pragma unroll
    for (int m = 0; m < 8; ++m) {
        #pragma unroll
        for (int j = 0; j < 4; ++j) {
            int r = wm + m * 16 + (lane >> 4) * 4 + j;
            int pos = rs + r;
            if (pos >= rend) continue;
            int pr = perm[pos];
            int t = pr >> 1;
            float w = tk_w[pr];
            #pragma unroll
            for (int n = 0; n < 4; ++n) {
                int col = n0 + wn + n * 16 + (lane & 15);
                float base = (ks == 0) ? b2[e * D_DIM + col] : 0.f;
                float v = (acc[m][n][j] + base) * w;
                atomicAdd(&out[(size_t)t * D_DIM + col], v);
            }
        }
    }
}

extern "C" void kernel_launch(void* const* d_in, const int* in_sizes, int n_in,
                              void* d_out, int out_size, void* d_ws, size_t ws_size,
                              hipStream_t stream)
{
    const float* x     = (const float*)d_in[0];
    const float* noise = (const float*)d_in[1];
    const float* Wg    = (const float*)d_in[2];
    const float* bg    = (const float*)d_in[3];
    const float* Wn    = (const float*)d_in[4];
    const float* bn    = (const float*)d_in[5];
    const float* W1    = (const float*)d_in[6];
    const float* b1    = (const float*)d_in[7];
    const float* W2    = (const float*)d_in[8];
    const float* b2    = (const float*)d_in[9];

    float* out       = (float*)d_out;
    float* out_noisy = out + (size_t)T_TOK * D_DIM;
    float* out_gate  = out_noisy + (size_t)T_TOK * E_NUM;

    char* ws = (char*)d_ws;
    int*   tk_idx = (int*)ws;
    float* tk_w   = (float*)(ws + 32768);
    int*   perm   = (int*)(ws + 65536);
    int*   meta   = (int*)(ws + 98304);
    size_t off = 131072;
    unsigned short* xb   = (unsigned short*)(ws + off); off += (size_t)T_TOK * D_DIM * 2;
    unsigned short* W1T  = (unsigned short*)(ws + off); off += (size_t)E_NUM * F_DIM * D_DIM * 2;
    unsigned short* W2T  = (unsigned short*)(ws + off); off += (size_t)E_NUM * D_DIM * F_DIM * 2;
    unsigned short* hbuf = (unsigned short*)(ws + off); off += (size_t)NPAIR * F_DIM * 2;

    hipMemsetAsync(d_out, 0, (size_t)out_size * sizeof(float), stream);

    router_convert_kernel<<<T_TOK / 4, 256, 0, stream>>>(x, noise, Wg, bg, Wn, bn,
                                                         out_noisy, out_gate, tk_idx, tk_w, xb);
    scan_scatter_kernel<<<1, 256, 0, stream>>>(tk_idx, perm, meta);
    // W2T early (its L3 footprint precedes fc1's streaming); W1T right before fc1.
    transpose_kernel<<<dim3(D_DIM / 64, F_DIM / 64, E_NUM), 256, 0, stream>>>(W2, W2T, F_DIM, D_DIM);
    transpose_kernel<<<dim3(F_DIM / 64, D_DIM / 64, E_NUM), 256, 0, stream>>>(W1, W1T, D_DIM, F_DIM);

    fc1_kernel<<<NTMAX * 16, 512, 0, stream>>>(xb, W1T, b1, perm, meta, hbuf);
    fc2_kernel<<<NTMAX * 16, 512, 0, stream>>>(hbuf, W2T, b2, perm, tk_w, meta, out);
}

// Round 8
// 591.550 us; speedup vs baseline: 1.2393x; 1.1347x over previous
//
#include <hip/hip_runtime.h>
#include <hip/hip_bf16.h>

#define T_TOK 4096
#define D_DIM 1024
#define E_NUM 8
#define F_DIM 4096
#define NPAIR 8192

#define BM 256
#define BN 128
#define BK 64
#define NTMAX 40   // max tiles = 8192/256 + 8 experts of remainder slack

typedef float f32x4 __attribute__((ext_vector_type(4)));
typedef __bf16 bf16x8 __attribute__((ext_vector_type(8)));
typedef unsigned short u16x8 __attribute__((ext_vector_type(8)));
typedef unsigned short u16x4 __attribute__((ext_vector_type(4)));

__device__ __forceinline__ unsigned short f2bf(float f) {
    unsigned int u = __float_as_uint(f);
    u += 0x7fffu + ((u >> 16) & 1u);
    return (unsigned short)(u >> 16);
}

typedef const __attribute__((address_space(1))) void GV;
typedef __attribute__((address_space(3))) void LV;

__device__ __forceinline__ void load_lds16(const void* g, void* l) {
    __builtin_amdgcn_global_load_lds((GV*)g, (LV*)l, 16, 0, 0);
}

// Swizzled LDS fragment read: logical (row, colShort cs) lives at
// byte = row*128 + ((cs*2) ^ ((row&7)<<4)). Writer: gload_lds writes linearly;
// the per-lane GLOBAL source column carries the matching permutation (csw).
__device__ __forceinline__ bf16x8 lds_frag(const unsigned short* S, int row, int cs) {
    int byte = row * (BK * 2) + ((cs * 2) ^ ((row & 7) << 4));
    return *(const bf16x8*)((const char*)S + byte);
}

// ---------------- Router + x->bf16 convert: one wave per token ----------------
__global__ __launch_bounds__(256) void router_convert_kernel(
    const float* __restrict__ x, const float* __restrict__ noise,
    const float* __restrict__ Wg, const float* __restrict__ bg,
    const float* __restrict__ Wn, const float* __restrict__ bn,
    float* __restrict__ out_noisy, float* __restrict__ out_gate,
    int* __restrict__ tk_idx, float* __restrict__ tk_w,
    unsigned short* __restrict__ xb)
{
    int lane = threadIdx.x & 63;
    int t = blockIdx.x * 4 + (threadIdx.x >> 6);
    const float* xr = x + (size_t)t * D_DIM;
    unsigned short* xbr = xb + (size_t)t * D_DIM;

    #pragma unroll
    for (int r = 0; r < 4; ++r) {
        int d = r * 256 + lane * 4;
        float4 v = *(const float4*)(xr + d);
        u16x4 o;
        o[0] = f2bf(v.x); o[1] = f2bf(v.y); o[2] = f2bf(v.z); o[3] = f2bf(v.w);
        *(u16x4*)(xbr + d) = o;
    }

    float ag[E_NUM] = {}, an[E_NUM] = {};
    for (int it = 0; it < D_DIM / 64; ++it) {
        int d = it * 64 + lane;
        float xv = xr[d];
        float4 g0 = *(const float4*)(Wg + (size_t)d * E_NUM);
        float4 g1 = *(const float4*)(Wg + (size_t)d * E_NUM + 4);
        float4 m0 = *(const float4*)(Wn + (size_t)d * E_NUM);
        float4 m1 = *(const float4*)(Wn + (size_t)d * E_NUM + 4);
        ag[0] += xv * g0.x; ag[1] += xv * g0.y; ag[2] += xv * g0.z; ag[3] += xv * g0.w;
        ag[4] += xv * g1.x; ag[5] += xv * g1.y; ag[6] += xv * g1.z; ag[7] += xv * g1.w;
        an[0] += xv * m0.x; an[1] += xv * m0.y; an[2] += xv * m0.z; an[3] += xv * m0.w;
        an[4] += xv * m1.x; an[5] += xv * m1.y; an[6] += xv * m1.z; an[7] += xv * m1.w;
    }
    #pragma unroll
    for (int off = 32; off > 0; off >>= 1) {
        #pragma unroll
        for (int e = 0; e < E_NUM; ++e) {
            ag[e] += __shfl_xor(ag[e], off);
            an[e] += __shfl_xor(an[e], off);
        }
    }
    if (lane == 0) {
        float nz[E_NUM];
        #pragma unroll
        for (int e = 0; e < E_NUM; ++e) {
            float g = ag[e] + bg[e];
            float nn = an[e] + bn[e];
            float sp = fmaxf(nn, 0.f) + log1pf(expf(-fabsf(nn)));
            float z = g + noise[(size_t)t * E_NUM + e] * sp;
            out_gate[(size_t)t * E_NUM + e] = g;
            out_noisy[(size_t)t * E_NUM + e] = z;
            nz[e] = z;
        }
        int e0 = 0;
        #pragma unroll
        for (int e = 1; e < E_NUM; ++e) if (nz[e] > nz[e0]) e0 = e;
        int e1 = (e0 == 0) ? 1 : 0;
        #pragma unroll
        for (int e = 0; e < E_NUM; ++e) if (e != e0 && nz[e] > nz[e1]) e1 = e;
        float b = expf(nz[e1] - nz[e0]);  // <= 1
        float w0 = 1.f / (1.f + b);
        float w1 = b / (1.f + b);
        tk_idx[t * 2] = e0;  tk_idx[t * 2 + 1] = e1;
        tk_w[t * 2] = w0;    tk_w[t * 2 + 1] = w1;
    }
}

// ---------------- Deterministic group-by-expert (1 block) ----------------
__global__ __launch_bounds__(256) void scan_scatter_kernel(
    const int* __restrict__ tk_idx,
    int* __restrict__ perm, int* __restrict__ meta)
{
    __shared__ int cnt[256][E_NUM];
    __shared__ int soff[E_NUM];
    int tid = threadIdx.x;
    const int PPT = NPAIR / 256;
    int p0 = tid * PPT;

    int c[E_NUM] = {};
    for (int i = 0; i < PPT; ++i) c[tk_idx[p0 + i]]++;
    #pragma unroll
    for (int e = 0; e < E_NUM; ++e) cnt[tid][e] = c[e];
    __syncthreads();

    if (tid < E_NUM) {
        int s = 0;
        for (int j = 0; j < 256; ++j) { int v = cnt[j][tid]; cnt[j][tid] = s; s += v; }
        soff[tid] = s;
    }
    __syncthreads();

    if (tid == 0) {
        int off = 0, nt = 0;
        for (int e = 0; e < E_NUM; ++e) {
            int ce = soff[e];
            meta[1 + e] = off;
            meta[9 + e] = ce;
            for (int j = 0; j < ce; j += BM) {
                meta[32 + nt]  = e;
                meta[160 + nt] = off + j;
                meta[288 + nt] = off + ce;
                nt++;
            }
            off += ce;
        }
        meta[0] = nt;
    }
    __syncthreads();
    if (tid < E_NUM) soff[tid] = meta[1 + tid];
    __syncthreads();

    int pos[E_NUM];
    #pragma unroll
    for (int e = 0; e < E_NUM; ++e) pos[e] = soff[e] + cnt[tid][e];
    for (int i = 0; i < PPT; ++i) {
        int e = tk_idx[p0 + i];
        perm[pos[e]++] = p0 + i;
    }
}

// ---------------- W [E][R][C] f32 -> WT [E][C][R] bf16, 64x64 tiles ----------------
__global__ __launch_bounds__(256) void transpose_kernel(
    const float* __restrict__ W, unsigned short* __restrict__ WT, int R, int C)
{
    __shared__ float tile[64][65];
    int e = blockIdx.z;
    int c0 = blockIdx.x * 64, r0 = blockIdx.y * 64;
    int tx = threadIdx.x & 15, ty = threadIdx.x >> 4;
    const float* src = W + (size_t)e * R * C;
    #pragma unroll
    for (int j = 0; j < 4; ++j) {
        int r = ty + 16 * j;
        float4 v = *(const float4*)(src + (size_t)(r0 + r) * C + c0 + tx * 4);
        *(float4*)&tile[r][tx * 4] = v;
    }
    __syncthreads();
    unsigned short* dst = WT + (size_t)e * C * R;
    int sx = threadIdx.x & 7, sy = threadIdx.x >> 3;
    #pragma unroll
    for (int j = 0; j < 2; ++j) {
        int c = sy + 32 * j;
        u16x8 o;
        #pragma unroll
        for (int k = 0; k < 8; ++k) o[k] = f2bf(tile[sx * 8 + k][c]);
        *(u16x8*)(dst + (size_t)(c0 + c) * R + r0 + sx * 8) = o;
    }
}

// ---- One K-tile of the 3-buffer pipelined GEMM: 2 MFMA phases, stage split 3+3.
// Per wave: C = 64x64 (4m x 4n frags), A frags held across phases.
#define KTILE_BODY(ASRC_K, BSRC_K)                                                   \
    {                                                                                \
        const unsigned short* A = &AsAll[(t % 3) * (BM * BK)];                       \
        const unsigned short* B = &BsAll[(t % 3) * (BN * BK)];                       \
        if (t + 1 < NT) { asm volatile("s_waitcnt vmcnt(6)" ::: "memory"); }         \
        else            { asm volatile("s_waitcnt vmcnt(0)" ::: "memory"); }         \
        __builtin_amdgcn_s_barrier();                                                \
        if (t + 2 < NT) {                                                            \
            int k2 = (t + 2) * BK;                                                   \
            unsigned short* dA = &AsAll[((t + 2) % 3) * (BM * BK)];                  \
            load_lds16(ASRC_K(0, k2), dA + (tid + 0 * 512) * 8);                     \
            load_lds16(ASRC_K(1, k2), dA + (tid + 1 * 512) * 8);                     \
            load_lds16(ASRC_K(2, k2), dA + (tid + 2 * 512) * 8);                     \
        }                                                                            \
        bf16x8 af[4][2], bf0[2][2];                                                  \
        _Pragma("unroll")                                                            \
        for (int m = 0; m < 4; ++m)                                                  \
            _Pragma("unroll")                                                        \
            for (int k = 0; k < 2; ++k)                                              \
                af[m][k] = lds_frag(A, wm + m * 16 + (lane & 15), k * 32 + (lane >> 4) * 8); \
        _Pragma("unroll")                                                            \
        for (int n = 0; n < 2; ++n)                                                  \
            _Pragma("unroll")                                                        \
            for (int k = 0; k < 2; ++k)                                              \
                bf0[n][k] = lds_frag(B, wn + n * 16 + (lane & 15), k * 32 + (lane >> 4) * 8); \
        __builtin_amdgcn_s_setprio(1);                                               \
        _Pragma("unroll")                                                            \
        for (int m = 0; m < 4; ++m)                                                  \
            _Pragma("unroll")                                                        \
            for (int n = 0; n < 2; ++n)                                              \
                _Pragma("unroll")                                                    \
                for (int k = 0; k < 2; ++k)                                          \
                    acc[m][n] = __builtin_amdgcn_mfma_f32_16x16x32_bf16(af[m][k], bf0[n][k], acc[m][n], 0, 0, 0); \
        __builtin_amdgcn_s_setprio(0);                                               \
        if (t + 2 < NT) {                                                            \
            int k2 = (t + 2) * BK;                                                   \
            unsigned short* dA = &AsAll[((t + 2) % 3) * (BM * BK)];                  \
            unsigned short* dB = &BsAll[((t + 2) % 3) * (BN * BK)];                  \
            load_lds16(ASRC_K(3, k2), dA + (tid + 3 * 512) * 8);                     \
            load_lds16(BSRC_K(0, k2), dB + (tid + 0 * 512) * 8);                     \
            load_lds16(BSRC_K(1, k2), dB + (tid + 1 * 512) * 8);                     \
        }                                                                            \
        bf16x8 bf1[2][2];                                                            \
        _Pragma("unroll")                                                            \
        for (int n = 0; n < 2; ++n)                                                  \
            _Pragma("unroll")                                                        \
            for (int k = 0; k < 2; ++k)                                              \
                bf1[n][k] = lds_frag(B, wn + (n + 2) * 16 + (lane & 15), k * 32 + (lane >> 4) * 8); \
        __builtin_amdgcn_s_setprio(1);                                               \
        _Pragma("unroll")                                                            \
        for (int m = 0; m < 4; ++m)                                                  \
            _Pragma("unroll")                                                        \
            for (int n = 0; n < 2; ++n)                                              \
                _Pragma("unroll")                                                    \
                for (int k = 0; k < 2; ++k)                                          \
                    acc[m][n + 2] = __builtin_amdgcn_mfma_f32_16x16x32_bf16(af[m][k], bf1[n][k], acc[m][n + 2], 0, 0, 0); \
        __builtin_amdgcn_s_setprio(0);                                               \
    }

// ---------------- FC1: h = gelu(x @ W1 + b1), 256x128, 3-buf prefetch-2 ----------------
__global__ __launch_bounds__(512, 1) void fc1_kernel(
    const unsigned short* __restrict__ xb,    // [T][D] bf16
    const unsigned short* __restrict__ W1T,   // [E][F][D] bf16
    const float* __restrict__ b1,             // [E][F]
    const int* __restrict__ perm,
    const int* __restrict__ meta,
    unsigned short* __restrict__ h)           // [NPAIR][F] bf16
{
    const int nwg = NTMAX * 32;               // 1280, % 8 == 0
    int bid = blockIdx.x;
    int wg = (bid & 7) * (nwg >> 3) + (bid >> 3);
    int tile = wg >> 5;                       // tile-major: A panel shared within XCD chunk
    int n0 = (wg & 31) * BN;
    if (tile >= meta[0]) return;
    int e    = meta[32 + tile];
    int rs   = meta[160 + tile];
    int rend = meta[288 + tile];

    __shared__ __align__(16) unsigned short AsAll[3 * BM * BK];   // 96 KB
    __shared__ __align__(16) unsigned short BsAll[3 * BN * BK];   // 48 KB

    int tid = threadIdx.x, lane = tid & 63, wv = tid >> 6;        // 8 waves
    int wm = (wv >> 1) * 64, wn = (wv & 1) * 64;                  // 4M x 2N of 64x64
    int csw = ((tid & 7) ^ ((tid >> 3) & 7)) * 8;  // pre-swizzled global col

    const unsigned short* asrc[4];
    const unsigned short* bsrc[2];
    #pragma unroll
    for (int i = 0; i < 4; ++i) {
        int row = (tid >> 3) + i * 64;
        int pos = rs + row; if (pos >= NPAIR) pos = NPAIR - 1;
        int tt = perm[pos] >> 1;
        asrc[i] = xb + (size_t)tt * D_DIM + csw;
    }
    #pragma unroll
    for (int i = 0; i < 2; ++i) {
        int row = (tid >> 3) + i * 64;
        bsrc[i] = W1T + ((size_t)e * F_DIM + n0 + row) * D_DIM + csw;
    }

#define ASRC1(i, k2) (asrc[i] + (k2))
#define BSRC1(i, k2) (bsrc[i] + (k2))

    f32x4 acc[4][4] = {};
    const int NT = D_DIM / BK;   // 16

    // prologue: stage tiles 0 and 1 (6 instr each per wave)
    {
        unsigned short* dA = &AsAll[0];  unsigned short* dB = &BsAll[0];
        #pragma unroll
        for (int i = 0; i < 4; ++i) load_lds16(ASRC1(i, 0), dA + (tid + i * 512) * 8);
        #pragma unroll
        for (int i = 0; i < 2; ++i) load_lds16(BSRC1(i, 0), dB + (tid + i * 512) * 8);
        dA = &AsAll[BM * BK];  dB = &BsAll[BN * BK];
        #pragma unroll
        for (int i = 0; i < 4; ++i) load_lds16(ASRC1(i, BK), dA + (tid + i * 512) * 8);
        #pragma unroll
        for (int i = 0; i < 2; ++i) load_lds16(BSRC1(i, BK), dB + (tid + i * 512) * 8);
    }

    for (int t = 0; t < NT; ++t) {
        KTILE_BODY(ASRC1, BSRC1)
    }
#undef ASRC1
#undef BSRC1

    #pragma unroll
    for (int m = 0; m < 4; ++m) {
        #pragma unroll
        for (int j = 0; j < 4; ++j) {
            int r = wm + m * 16 + (lane >> 4) * 4 + j;
            int pos = rs + r;
            if (pos >= rend) continue;
            #pragma unroll
            for (int n = 0; n < 4; ++n) {
                int col = n0 + wn + n * 16 + (lane & 15);
                float v = acc[m][n][j] + b1[e * F_DIM + col];
                v = 0.5f * v * (1.f + erff(v * 0.70710678118654752f));  // exact GELU
                h[(size_t)pos * F_DIM + col] = f2bf(v);
            }
        }
    }
}

// ---------------- FC2: out += w * (h @ W2 + b2), 256x128, splitK=2, 3-buf ----------------
__global__ __launch_bounds__(512, 1) void fc2_kernel(
    const unsigned short* __restrict__ h,     // [NPAIR][F] bf16 (grouped rows contiguous)
    const unsigned short* __restrict__ W2T,   // [E][D][F] bf16
    const float* __restrict__ b2,             // [E][D]
    const int* __restrict__ perm,
    const float* __restrict__ tk_w,
    const int* __restrict__ meta,
    float* __restrict__ out)                  // [T][D] fp32 (zeroed)
{
    const int nwg = NTMAX * 16;               // 640, % 8 == 0
    int bid = blockIdx.x;
    int wg = (bid & 7) * (nwg >> 3) + (bid >> 3);
    int tile = wg >> 4;                       // tile-major
    int rem  = wg & 15;
    int n0 = (rem >> 1) * BN;                 // 8 D-blocks of 128
    int ks = rem & 1;                         // splitK=2
    if (tile >= meta[0]) return;
    int e    = meta[32 + tile];
    int rs   = meta[160 + tile];
    int rend = meta[288 + tile];
    int kbeg = ks * (F_DIM / 2);

    __shared__ __align__(16) unsigned short AsAll[3 * BM * BK];
    __shared__ __align__(16) unsigned short BsAll[3 * BN * BK];

    int tid = threadIdx.x, lane = tid & 63, wv = tid >> 6;
    int wm = (wv >> 1) * 64, wn = (wv & 1) * 64;
    int csw = ((tid & 7) ^ ((tid >> 3) & 7)) * 8;

    const unsigned short* asrc[4];
    const unsigned short* bsrc[2];
    #pragma unroll
    for (int i = 0; i < 4; ++i) {
        int row = (tid >> 3) + i * 64;
        int pos = rs + row; if (pos >= NPAIR) pos = NPAIR - 1;
        asrc[i] = h + (size_t)pos * F_DIM + kbeg + csw;    // grouped rows: contiguous
    }
    #pragma unroll
    for (int i = 0; i < 2; ++i) {
        int row = (tid >> 3) + i * 64;
        bsrc[i] = W2T + ((size_t)e * D_DIM + n0 + row) * F_DIM + kbeg + csw;
    }

#define ASRC2(i, k2) (asrc[i] + (k2))
#define BSRC2(i, k2) (bsrc[i] + (k2))

    f32x4 acc[4][4] = {};
    const int NT = (F_DIM / 2) / BK;   // 32

    {
        unsigned short* dA = &AsAll[0];  unsigned short* dB = &BsAll[0];
        #pragma unroll
        for (int i = 0; i < 4; ++i) load_lds16(ASRC2(i, 0), dA + (tid + i * 512) * 8);
        #pragma unroll
        for (int i = 0; i < 2; ++i) load_lds16(BSRC2(i, 0), dB + (tid + i * 512) * 8);
        dA = &AsAll[BM * BK];  dB = &BsAll[BN * BK];
        #pragma unroll
        for (int i = 0; i < 4; ++i) load_lds16(ASRC2(i, BK), dA + (tid + i * 512) * 8);
        #pragma unroll
        for (int i = 0; i < 2; ++i) load_lds16(BSRC2(i, BK), dB + (tid + i * 512) * 8);
    }

    for (int t = 0; t < NT; ++t) {
        KTILE_BODY(ASRC2, BSRC2)
    }
#undef ASRC2
#undef BSRC2

    #pragma unroll
    for (int m = 0; m < 4; ++m) {
        #pragma unroll
        for (int j = 0; j < 4; ++j) {
            int r = wm + m * 16 + (lane >> 4) * 4 + j;
            int pos = rs + r;
            if (pos >= rend) continue;
            int pr = perm[pos];
            int t2 = pr >> 1;
            float w = tk_w[pr];
            #pragma unroll
            for (int n = 0; n < 4; ++n) {
                int col = n0 + wn + n * 16 + (lane & 15);
                float base = (ks == 0) ? b2[e * D_DIM + col] : 0.f;
                float v = (acc[m][n][j] + base) * w;
                atomicAdd(&out[(size_t)t2 * D_DIM + col], v);
            }
        }
    }
}

extern "C" void kernel_launch(void* const* d_in, const int* in_sizes, int n_in,
                              void* d_out, int out_size, void* d_ws, size_t ws_size,
                              hipStream_t stream)
{
    const float* x     = (const float*)d_in[0];
    const float* noise = (const float*)d_in[1];
    const float* Wg    = (const float*)d_in[2];
    const float* bg    = (const float*)d_in[3];
    const float* Wn    = (const float*)d_in[4];
    const float* bn    = (const float*)d_in[5];
    const float* W1    = (const float*)d_in[6];
    const float* b1    = (const float*)d_in[7];
    const float* W2    = (const float*)d_in[8];
    const float* b2    = (const float*)d_in[9];

    float* out       = (float*)d_out;
    float* out_noisy = out + (size_t)T_TOK * D_DIM;
    float* out_gate  = out_noisy + (size_t)T_TOK * E_NUM;

    char* ws = (char*)d_ws;
    int*   tk_idx = (int*)ws;
    float* tk_w   = (float*)(ws + 32768);
    int*   perm   = (int*)(ws + 65536);
    int*   meta   = (int*)(ws + 98304);
    size_t off = 131072;
    unsigned short* xb   = (unsigned short*)(ws + off); off += (size_t)T_TOK * D_DIM * 2;
    unsigned short* W1T  = (unsigned short*)(ws + off); off += (size_t)E_NUM * F_DIM * D_DIM * 2;
    unsigned short* W2T  = (unsigned short*)(ws + off); off += (size_t)E_NUM * D_DIM * F_DIM * 2;
    unsigned short* hbuf = (unsigned short*)(ws + off); off += (size_t)NPAIR * F_DIM * 2;

    hipMemsetAsync(d_out, 0, (size_t)out_size * sizeof(float), stream);

    router_convert_kernel<<<T_TOK / 4, 256, 0, stream>>>(x, noise, Wg, bg, Wn, bn,
                                                         out_noisy, out_gate, tk_idx, tk_w, xb);
    scan_scatter_kernel<<<1, 256, 0, stream>>>(tk_idx, perm, meta);
    // W2T early (its L3 footprint precedes fc1's streaming); W1T right before fc1.
    transpose_kernel<<<dim3(D_DIM / 64, F_DIM / 64, E_NUM), 256, 0, stream>>>(W2, W2T, F_DIM, D_DIM);
    transpose_kernel<<<dim3(F_DIM / 64, D_DIM / 64, E_NUM), 256, 0, stream>>>(W1, W1T, D_DIM, F_DIM);

    fc1_kernel<<<NTMAX * 32, 512, 0, stream>>>(xb, W1T, b1, perm, meta, hbuf);
    fc2_kernel<<<NTMAX * 16, 512, 0, stream>>>(hbuf, W2T, b2, perm, tk_w, meta, out);
}

// Round 9
// 501.151 us; speedup vs baseline: 1.4629x; 1.1804x over previous
//
#include <hip/hip_runtime.h>
#include <hip/hip_bf16.h>

#define T_TOK 4096
#define D_DIM 1024
#define E_NUM 8
#define F_DIM 4096
#define NPAIR 8192

#define BM 256
#define BN 256
#define BK 64
#define NTMAX 40   // max tiles = 8192/256 + 8 experts of remainder slack

typedef float f32x4 __attribute__((ext_vector_type(4)));
typedef __bf16 bf16x8 __attribute__((ext_vector_type(8)));
typedef unsigned short u16x8 __attribute__((ext_vector_type(8)));
typedef unsigned short u16x4 __attribute__((ext_vector_type(4)));

__device__ __forceinline__ unsigned short f2bf(float f) {
    unsigned int u = __float_as_uint(f);
    u += 0x7fffu + ((u >> 16) & 1u);
    return (unsigned short)(u >> 16);
}

typedef const __attribute__((address_space(1))) void GV;
typedef __attribute__((address_space(3))) void LV;

__device__ __forceinline__ void load_lds16(const void* g, void* l) {
    __builtin_amdgcn_global_load_lds((GV*)g, (LV*)l, 16, 0, 0);
}

// Swizzled LDS fragment read: logical (row, colShort cs) lives at
// byte = row*128 + ((cs*2) ^ ((row&7)<<4)). Writer: gload_lds writes linearly
// at slot s of row; slot s holds logical col (s ^ (row&7))*8 shorts, so the
// per-lane GLOBAL source column csw = (s ^ (row&7))*8 carries the permutation.
__device__ __forceinline__ bf16x8 lds_frag(const unsigned short* S, int row, int cs) {
    int byte = row * (BK * 2) + ((cs * 2) ^ ((row & 7) << 4));
    return *(const bf16x8*)((const char*)S + byte);
}

// ---------------- Router + x->bf16 convert: one wave per token ----------------
__global__ __launch_bounds__(256) void router_convert_kernel(
    const float* __restrict__ x, const float* __restrict__ noise,
    const float* __restrict__ Wg, const float* __restrict__ bg,
    const float* __restrict__ Wn, const float* __restrict__ bn,
    float* __restrict__ out_noisy, float* __restrict__ out_gate,
    int* __restrict__ tk_idx, float* __restrict__ tk_w,
    unsigned short* __restrict__ xb)
{
    int lane = threadIdx.x & 63;
    int t = blockIdx.x * 4 + (threadIdx.x >> 6);
    const float* xr = x + (size_t)t * D_DIM;
    unsigned short* xbr = xb + (size_t)t * D_DIM;

    #pragma unroll
    for (int r = 0; r < 4; ++r) {
        int d = r * 256 + lane * 4;
        float4 v = *(const float4*)(xr + d);
        u16x4 o;
        o[0] = f2bf(v.x); o[1] = f2bf(v.y); o[2] = f2bf(v.z); o[3] = f2bf(v.w);
        *(u16x4*)(xbr + d) = o;
    }

    float ag[E_NUM] = {}, an[E_NUM] = {};
    for (int it = 0; it < D_DIM / 64; ++it) {
        int d = it * 64 + lane;
        float xv = xr[d];
        float4 g0 = *(const float4*)(Wg + (size_t)d * E_NUM);
        float4 g1 = *(const float4*)(Wg + (size_t)d * E_NUM + 4);
        float4 m0 = *(const float4*)(Wn + (size_t)d * E_NUM);
        float4 m1 = *(const float4*)(Wn + (size_t)d * E_NUM + 4);
        ag[0] += xv * g0.x; ag[1] += xv * g0.y; ag[2] += xv * g0.z; ag[3] += xv * g0.w;
        ag[4] += xv * g1.x; ag[5] += xv * g1.y; ag[6] += xv * g1.z; ag[7] += xv * g1.w;
        an[0] += xv * m0.x; an[1] += xv * m0.y; an[2] += xv * m0.z; an[3] += xv * m0.w;
        an[4] += xv * m1.x; an[5] += xv * m1.y; an[6] += xv * m1.z; an[7] += xv * m1.w;
    }
    #pragma unroll
    for (int off = 32; off > 0; off >>= 1) {
        #pragma unroll
        for (int e = 0; e < E_NUM; ++e) {
            ag[e] += __shfl_xor(ag[e], off);
            an[e] += __shfl_xor(an[e], off);
        }
    }
    if (lane == 0) {
        float nz[E_NUM];
        #pragma unroll
        for (int e = 0; e < E_NUM; ++e) {
            float g = ag[e] + bg[e];
            float nn = an[e] + bn[e];
            float sp = fmaxf(nn, 0.f) + log1pf(expf(-fabsf(nn)));
            float z = g + noise[(size_t)t * E_NUM + e] * sp;
            out_gate[(size_t)t * E_NUM + e] = g;
            out_noisy[(size_t)t * E_NUM + e] = z;
            nz[e] = z;
        }
        int e0 = 0;
        #pragma unroll
        for (int e = 1; e < E_NUM; ++e) if (nz[e] > nz[e0]) e0 = e;
        int e1 = (e0 == 0) ? 1 : 0;
        #pragma unroll
        for (int e = 0; e < E_NUM; ++e) if (e != e0 && nz[e] > nz[e1]) e1 = e;
        float b = expf(nz[e1] - nz[e0]);  // <= 1
        float w0 = 1.f / (1.f + b);
        float w1 = b / (1.f + b);
        tk_idx[t * 2] = e0;  tk_idx[t * 2 + 1] = e1;
        tk_w[t * 2] = w0;    tk_w[t * 2 + 1] = w1;
    }
}

// ---------------- Deterministic group-by-expert (1 block) ----------------
__global__ __launch_bounds__(256) void scan_scatter_kernel(
    const int* __restrict__ tk_idx,
    int* __restrict__ perm, int* __restrict__ meta)
{
    __shared__ int cnt[256][E_NUM];
    __shared__ int soff[E_NUM];
    int tid = threadIdx.x;
    const int PPT = NPAIR / 256;
    int p0 = tid * PPT;

    int c[E_NUM] = {};
    for (int i = 0; i < PPT; ++i) c[tk_idx[p0 + i]]++;
    #pragma unroll
    for (int e = 0; e < E_NUM; ++e) cnt[tid][e] = c[e];
    __syncthreads();

    if (tid < E_NUM) {
        int s = 0;
        for (int j = 0; j < 256; ++j) { int v = cnt[j][tid]; cnt[j][tid] = s; s += v; }
        soff[tid] = s;
    }
    __syncthreads();

    if (tid == 0) {
        int off = 0, nt = 0;
        for (int e = 0; e < E_NUM; ++e) {
            int ce = soff[e];
            meta[1 + e] = off;
            meta[9 + e] = ce;
            for (int j = 0; j < ce; j += BM) {
                meta[32 + nt]  = e;
                meta[160 + nt] = off + j;
                meta[288 + nt] = off + ce;
                nt++;
            }
            off += ce;
        }
        meta[0] = nt;
    }
    __syncthreads();
    if (tid < E_NUM) soff[tid] = meta[1 + tid];
    __syncthreads();

    int pos[E_NUM];
    #pragma unroll
    for (int e = 0; e < E_NUM; ++e) pos[e] = soff[e] + cnt[tid][e];
    for (int i = 0; i < PPT; ++i) {
        int e = tk_idx[p0 + i];
        perm[pos[e]++] = p0 + i;
    }
}

// ---------------- W [E][R][C] f32 -> WT [E][C][R] bf16, 64x64 tiles ----------------
__global__ __launch_bounds__(256) void transpose_kernel(
    const float* __restrict__ W, unsigned short* __restrict__ WT, int R, int C)
{
    __shared__ float tile[64][65];
    int e = blockIdx.z;
    int c0 = blockIdx.x * 64, r0 = blockIdx.y * 64;
    int tx = threadIdx.x & 15, ty = threadIdx.x >> 4;
    const float* src = W + (size_t)e * R * C;
    #pragma unroll
    for (int j = 0; j < 4; ++j) {
        int r = ty + 16 * j;
        float4 v = *(const float4*)(src + (size_t)(r0 + r) * C + c0 + tx * 4);
        *(float4*)&tile[r][tx * 4] = v;
    }
    __syncthreads();
    unsigned short* dst = WT + (size_t)e * C * R;
    int sx = threadIdx.x & 7, sy = threadIdx.x >> 3;
    #pragma unroll
    for (int j = 0; j < 2; ++j) {
        int c = sy + 32 * j;
        u16x8 o;
        #pragma unroll
        for (int k = 0; k < 8; ++k) o[k] = f2bf(tile[sx * 8 + k][c]);
        *(u16x8*)(dst + (size_t)(c0 + c) * R + r0 + sx * 8) = o;
    }
}

// ---- per-wave 64x64 C over one staged K-tile (16 waves: 4M x 4N = 256x256) ----
#define GEMM_COMPUTE() do {                                                                \
    _Pragma("unroll")                                                                      \
    for (int kk = 0; kk < BK; kk += 32) {                                                  \
        bf16x8 af[4], bf[4];                                                               \
        _Pragma("unroll")                                                                  \
        for (int m_ = 0; m_ < 4; ++m_)                                                     \
            af[m_] = lds_frag(As, wm + m_ * 16 + (lane & 15), kk + (lane >> 4) * 8);       \
        _Pragma("unroll")                                                                  \
        for (int n_ = 0; n_ < 4; ++n_)                                                     \
            bf[n_] = lds_frag(Bs, wn + n_ * 16 + (lane & 15), kk + (lane >> 4) * 8);       \
        _Pragma("unroll")                                                                  \
        for (int m_ = 0; m_ < 4; ++m_)                                                     \
            _Pragma("unroll")                                                              \
            for (int n_ = 0; n_ < 4; ++n_)                                                 \
                acc[m_][n_] = __builtin_amdgcn_mfma_f32_16x16x32_bf16(af[m_], bf[n_],      \
                                                                      acc[m_][n_], 0, 0, 0); \
    }                                                                                      \
} while (0)

// ---------------- FC1: h = gelu(x @ W1 + b1), 256x256, 1024 thr, single-buffer ----------------
__global__ __launch_bounds__(1024, 4) void fc1_kernel(
    const unsigned short* __restrict__ xb,    // [T][D] bf16
    const unsigned short* __restrict__ W1T,   // [E][F][D] bf16
    const float* __restrict__ b1,             // [E][F]
    const int* __restrict__ perm,
    const int* __restrict__ meta,
    unsigned short* __restrict__ h)           // [NPAIR][F] bf16
{
    const int nwg = NTMAX * 16;               // 640, % 8 == 0
    int bid = blockIdx.x;
    int wg = (bid & 7) * (nwg >> 3) + (bid >> 3);
    int tile = wg >> 4;                       // tile-major: 16 consecutive wg share A panel
    int n0 = (wg & 15) * BN;
    if (tile >= meta[0]) return;
    int e    = meta[32 + tile];
    int rs   = meta[160 + tile];
    int rend = meta[288 + tile];

    __shared__ __align__(16) unsigned short As[BM * BK];   // 32 KB
    __shared__ __align__(16) unsigned short Bs[BN * BK];   // 32 KB

    int tid = threadIdx.x, lane = tid & 63, wv = tid >> 6;  // 16 waves
    int wm = (wv >> 2) * 64, wn = (wv & 3) * 64;
    int s = tid & 7;

    const unsigned short* asrc[2];
    const unsigned short* bsrc[2];
    #pragma unroll
    for (int i = 0; i < 2; ++i) {
        int row = (tid >> 3) + i * 128;
        int csw = (s ^ (row & 7)) * 8;        // pre-swizzled global col (shorts)
        int pos = rs + row; if (pos >= NPAIR) pos = NPAIR - 1;
        int tt = perm[pos] >> 1;
        asrc[i] = xb + (size_t)tt * D_DIM + csw;
        bsrc[i] = W1T + ((size_t)e * F_DIM + n0 + row) * D_DIM + csw;
    }

    f32x4 acc[4][4] = {};

    const int NT = D_DIM / BK;   // 16
    for (int t = 0; t < NT; ++t) {
        int k0 = t * BK;
        #pragma unroll
        for (int i = 0; i < 2; ++i) {
            load_lds16(asrc[i] + k0, &As[(tid + i * 1024) * 8]);
            load_lds16(bsrc[i] + k0, &Bs[(tid + i * 1024) * 8]);
        }
        asm volatile("s_waitcnt vmcnt(0)" ::: "memory");
        __builtin_amdgcn_s_barrier();
        __builtin_amdgcn_s_setprio(1);
        GEMM_COMPUTE();
        __builtin_amdgcn_s_setprio(0);
        asm volatile("s_waitcnt lgkmcnt(0)" ::: "memory");
        __builtin_amdgcn_s_barrier();   // all waves done reading before next stage overwrites
    }

    #pragma unroll
    for (int m = 0; m < 4; ++m) {
        #pragma unroll
        for (int j = 0; j < 4; ++j) {
            int r = wm + m * 16 + (lane >> 4) * 4 + j;
            int pos = rs + r;
            if (pos >= rend) continue;
            #pragma unroll
            for (int n = 0; n < 4; ++n) {
                int col = n0 + wn + n * 16 + (lane & 15);
                float v = acc[m][n][j] + b1[e * F_DIM + col];
                v = 0.5f * v * (1.f + erff(v * 0.70710678118654752f));  // exact GELU
                h[(size_t)pos * F_DIM + col] = f2bf(v);
            }
        }
    }
}

// ---------------- FC2: out += w * (h @ W2 + b2), 256x256, splitK=2 ----------------
__global__ __launch_bounds__(1024, 4) void fc2_kernel(
    const unsigned short* __restrict__ h,     // [NPAIR][F] bf16 (grouped rows contiguous)
    const unsigned short* __restrict__ W2T,   // [E][D][F] bf16
    const float* __restrict__ b2,             // [E][D]
    const int* __restrict__ perm,
    const float* __restrict__ tk_w,
    const int* __restrict__ meta,
    float* __restrict__ out)                  // [T][D] fp32 (zeroed)
{
    const int nwg = NTMAX * 8;                // 40 tiles x 4 n0 x 2 ks = 320, % 8 == 0
    int bid = blockIdx.x;
    int wg = (bid & 7) * (nwg >> 3) + (bid >> 3);
    int tile = wg >> 3;                       // tile-major: 8 consecutive wg share A panel
    int rem  = wg & 7;
    int n0 = (rem >> 1) * BN;                 // 4 D-blocks of 256
    int ks = rem & 1;                         // splitK=2
    if (tile >= meta[0]) return;
    int e    = meta[32 + tile];
    int rs   = meta[160 + tile];
    int rend = meta[288 + tile];
    int kbeg = ks * (F_DIM / 2);

    __shared__ __align__(16) unsigned short As[BM * BK];
    __shared__ __align__(16) unsigned short Bs[BN * BK];

    int tid = threadIdx.x, lane = tid & 63, wv = tid >> 6;
    int wm = (wv >> 2) * 64, wn = (wv & 3) * 64;
    int s = tid & 7;

    const unsigned short* asrc[2];
    const unsigned short* bsrc[2];
    #pragma unroll
    for (int i = 0; i < 2; ++i) {
        int row = (tid >> 3) + i * 128;
        int csw = (s ^ (row & 7)) * 8;
        int pos = rs + row; if (pos >= NPAIR) pos = NPAIR - 1;
        asrc[i] = h + (size_t)pos * F_DIM + kbeg + csw;     // grouped rows: contiguous
        bsrc[i] = W2T + ((size_t)e * D_DIM + n0 + row) * F_DIM + kbeg + csw;
    }

    f32x4 acc[4][4] = {};

    const int NT = (F_DIM / 2) / BK;   // 32
    for (int t = 0; t < NT; ++t) {
        int k0 = t * BK;
        #pragma unroll
        for (int i = 0; i < 2; ++i) {
            load_lds16(asrc[i] + k0, &As[(tid + i * 1024) * 8]);
            load_lds16(bsrc[i] + k0, &Bs[(tid + i * 1024) * 8]);
        }
        asm volatile("s_waitcnt vmcnt(0)" ::: "memory");
        __builtin_amdgcn_s_barrier();
        __builtin_amdgcn_s_setprio(1);
        GEMM_COMPUTE();
        __builtin_amdgcn_s_setprio(0);
        asm volatile("s_waitcnt lgkmcnt(0)" ::: "memory");
        __builtin_amdgcn_s_barrier();
    }

    #pragma unroll
    for (int m = 0; m < 4; ++m) {
        #pragma unroll
        for (int j = 0; j < 4; ++j) {
            int r = wm + m * 16 + (lane >> 4) * 4 + j;
            int pos = rs + r;
            if (pos >= rend) continue;
            int pr = perm[pos];
            int t2 = pr >> 1;
            float w = tk_w[pr];
            #pragma unroll
            for (int n = 0; n < 4; ++n) {
                int col = n0 + wn + n * 16 + (lane & 15);
                float base = (ks == 0) ? b2[e * D_DIM + col] : 0.f;
                float v = (acc[m][n][j] + base) * w;
                atomicAdd(&out[(size_t)t2 * D_DIM + col], v);
            }
        }
    }
}

extern "C" void kernel_launch(void* const* d_in, const int* in_sizes, int n_in,
                              void* d_out, int out_size, void* d_ws, size_t ws_size,
                              hipStream_t stream)
{
    const float* x     = (const float*)d_in[0];
    const float* noise = (const float*)d_in[1];
    const float* Wg    = (const float*)d_in[2];
    const float* bg    = (const float*)d_in[3];
    const float* Wn    = (const float*)d_in[4];
    const float* bn    = (const float*)d_in[5];
    const float* W1    = (const float*)d_in[6];
    const float* b1    = (const float*)d_in[7];
    const float* W2    = (const float*)d_in[8];
    const float* b2    = (const float*)d_in[9];

    float* out       = (float*)d_out;
    float* out_noisy = out + (size_t)T_TOK * D_DIM;
    float* out_gate  = out_noisy + (size_t)T_TOK * E_NUM;

    char* ws = (char*)d_ws;
    int*   tk_idx = (int*)ws;
    float* tk_w   = (float*)(ws + 32768);
    int*   perm   = (int*)(ws + 65536);
    int*   meta   = (int*)(ws + 98304);
    size_t off = 131072;
    unsigned short* xb   = (unsigned short*)(ws + off); off += (size_t)T_TOK * D_DIM * 2;
    unsigned short* W1T  = (unsigned short*)(ws + off); off += (size_t)E_NUM * F_DIM * D_DIM * 2;
    unsigned short* W2T  = (unsigned short*)(ws + off); off += (size_t)E_NUM * D_DIM * F_DIM * 2;
    unsigned short* hbuf = (unsigned short*)(ws + off); off += (size_t)NPAIR * F_DIM * 2;

    hipMemsetAsync(d_out, 0, (size_t)out_size * sizeof(float), stream);

    router_convert_kernel<<<T_TOK / 4, 256, 0, stream>>>(x, noise, Wg, bg, Wn, bn,
                                                         out_noisy, out_gate, tk_idx, tk_w, xb);
    scan_scatter_kernel<<<1, 256, 0, stream>>>(tk_idx, perm, meta);
    // W2T early (its L3 footprint precedes fc1's streaming); W1T right before fc1.
    transpose_kernel<<<dim3(D_DIM / 64, F_DIM / 64, E_NUM), 256, 0, stream>>>(W2, W2T, F_DIM, D_DIM);
    transpose_kernel<<<dim3(F_DIM / 64, D_DIM / 64, E_NUM), 256, 0, stream>>>(W1, W1T, D_DIM, F_DIM);

    fc1_kernel<<<NTMAX * 16, 1024, 0, stream>>>(xb, W1T, b1, perm, meta, hbuf);
    fc2_kernel<<<NTMAX * 8, 1024, 0, stream>>>(hbuf, W2T, b2, perm, tk_w, meta, out);
}

// Round 10
// 480.510 us; speedup vs baseline: 1.5257x; 1.0430x over previous
//
#include <hip/hip_runtime.h>
#include <hip/hip_bf16.h>

#define T_TOK 4096
#define D_DIM 1024
#define E_NUM 8
#define F_DIM 4096
#define NPAIR 8192

#define BM 256
#define BN 256
#define BK 32

typedef float f32x4 __attribute__((ext_vector_type(4)));
typedef __bf16 bf16x8 __attribute__((ext_vector_type(8)));
typedef unsigned short u16x8 __attribute__((ext_vector_type(8)));
typedef unsigned short u16x4 __attribute__((ext_vector_type(4)));

__device__ __forceinline__ unsigned short f2bf(float f) {
    unsigned int u = __float_as_uint(f);
    u += 0x7fffu + ((u >> 16) & 1u);
    return (unsigned short)(u >> 16);
}

typedef const __attribute__((address_space(1))) void GV;
typedef __attribute__((address_space(3))) void LV;

__device__ __forceinline__ void load_lds16(const void* g, void* l) {
    __builtin_amdgcn_global_load_lds((GV*)g, (LV*)l, 16, 0, 0);
}

// 4-slot XOR swizzle for BK=32 rows (row = 64 B = 4 x 16B slots).
// slot s of row r holds global col-block (s ^ swz4(r)); verified 2-way max
// bank aliasing on ds_read (free per m136). Writer: gload_lds writes linearly
// (wave base + lane*16B); the per-lane GLOBAL source column carries the perm.
__device__ __forceinline__ int swz4(int r) { return (r ^ (r >> 2)) & 3; }

__device__ __forceinline__ bf16x8 lds_frag32(const unsigned short* S, int row, int cb) {
    int byte = row * 64 + ((cb ^ swz4(row)) << 4);
    return *(const bf16x8*)((const char*)S + byte);
}

// ---------------- Router + x->bf16 convert: one wave per token ----------------
__global__ __launch_bounds__(256) void router_convert_kernel(
    const float* __restrict__ x, const float* __restrict__ noise,
    const float* __restrict__ Wg, const float* __restrict__ bg,
    const float* __restrict__ Wn, const float* __restrict__ bn,
    float* __restrict__ out_noisy, float* __restrict__ out_gate,
    int* __restrict__ tk_idx, float* __restrict__ tk_w,
    unsigned short* __restrict__ xb)
{
    int lane = threadIdx.x & 63;
    int t = blockIdx.x * 4 + (threadIdx.x >> 6);
    const float* xr = x + (size_t)t * D_DIM;
    unsigned short* xbr = xb + (size_t)t * D_DIM;

    #pragma unroll
    for (int r = 0; r < 4; ++r) {
        int d = r * 256 + lane * 4;
        float4 v = *(const float4*)(xr + d);
        u16x4 o;
        o[0] = f2bf(v.x); o[1] = f2bf(v.y); o[2] = f2bf(v.z); o[3] = f2bf(v.w);
        *(u16x4*)(xbr + d) = o;
    }

    float ag[E_NUM] = {}, an[E_NUM] = {};
    for (int it = 0; it < D_DIM / 64; ++it) {
        int d = it * 64 + lane;
        float xv = xr[d];
        float4 g0 = *(const float4*)(Wg + (size_t)d * E_NUM);
        float4 g1 = *(const float4*)(Wg + (size_t)d * E_NUM + 4);
        float4 m0 = *(const float4*)(Wn + (size_t)d * E_NUM);
        float4 m1 = *(const float4*)(Wn + (size_t)d * E_NUM + 4);
        ag[0] += xv * g0.x; ag[1] += xv * g0.y; ag[2] += xv * g0.z; ag[3] += xv * g0.w;
        ag[4] += xv * g1.x; ag[5] += xv * g1.y; ag[6] += xv * g1.z; ag[7] += xv * g1.w;
        an[0] += xv * m0.x; an[1] += xv * m0.y; an[2] += xv * m0.z; an[3] += xv * m0.w;
        an[4] += xv * m1.x; an[5] += xv * m1.y; an[6] += xv * m1.z; an[7] += xv * m1.w;
    }
    #pragma unroll
    for (int off = 32; off > 0; off >>= 1) {
        #pragma unroll
        for (int e = 0; e < E_NUM; ++e) {
            ag[e] += __shfl_xor(ag[e], off);
            an[e] += __shfl_xor(an[e], off);
        }
    }
    if (lane == 0) {
        float nz[E_NUM];
        #pragma unroll
        for (int e = 0; e < E_NUM; ++e) {
            float g = ag[e] + bg[e];
            float nn = an[e] + bn[e];
            float sp = fmaxf(nn, 0.f) + log1pf(expf(-fabsf(nn)));
            float z = g + noise[(size_t)t * E_NUM + e] * sp;
            out_gate[(size_t)t * E_NUM + e] = g;
            out_noisy[(size_t)t * E_NUM + e] = z;
            nz[e] = z;
        }
        int e0 = 0;
        #pragma unroll
        for (int e = 1; e < E_NUM; ++e) if (nz[e] > nz[e0]) e0 = e;
        int e1 = (e0 == 0) ? 1 : 0;
        #pragma unroll
        for (int e = 0; e < E_NUM; ++e) if (e != e0 && nz[e] > nz[e1]) e1 = e;
        float b = expf(nz[e1] - nz[e0]);  // <= 1
        float w0 = 1.f / (1.f + b);
        float w1 = b / (1.f + b);
        tk_idx[t * 2] = e0;  tk_idx[t * 2 + 1] = e1;
        tk_w[t * 2] = w0;    tk_w[t * 2 + 1] = w1;
    }
}

// ---------------- Deterministic group-by-expert (1 block) ----------------
__global__ __launch_bounds__(256) void scan_scatter_kernel(
    const int* __restrict__ tk_idx,
    int* __restrict__ perm, int* __restrict__ meta)
{
    __shared__ int cnt[256][E_NUM];
    __shared__ int soff[E_NUM];
    int tid = threadIdx.x;
    const int PPT = NPAIR / 256;
    int p0 = tid * PPT;

    int c[E_NUM] = {};
    for (int i = 0; i < PPT; ++i) c[tk_idx[p0 + i]]++;
    #pragma unroll
    for (int e = 0; e < E_NUM; ++e) cnt[tid][e] = c[e];
    __syncthreads();

    if (tid < E_NUM) {
        int s = 0;
        for (int j = 0; j < 256; ++j) { int v = cnt[j][tid]; cnt[j][tid] = s; s += v; }
        soff[tid] = s;
    }
    __syncthreads();

    if (tid == 0) {
        int off = 0, nt = 0;
        for (int e = 0; e < E_NUM; ++e) {
            int ce = soff[e];
            meta[1 + e] = off;
            meta[9 + e] = ce;
            for (int j = 0; j < ce; j += BM) {
                meta[32 + nt]  = e;
                meta[160 + nt] = off + j;
                meta[288 + nt] = off + ce;
                nt++;
            }
            off += ce;
        }
        meta[0] = nt;
    }
    __syncthreads();
    if (tid < E_NUM) soff[tid] = meta[1 + tid];
    __syncthreads();

    int pos[E_NUM];
    #pragma unroll
    for (int e = 0; e < E_NUM; ++e) pos[e] = soff[e] + cnt[tid][e];
    for (int i = 0; i < PPT; ++i) {
        int e = tk_idx[p0 + i];
        perm[pos[e]++] = p0 + i;
    }
}

// ---------------- W [E][R][C] f32 -> WT [E][C][R] bf16, 64x64 tiles ----------------
__global__ __launch_bounds__(256) void transpose_kernel(
    const float* __restrict__ W, unsigned short* __restrict__ WT, int R, int C)
{
    __shared__ float tile[64][65];
    int e = blockIdx.z;
    int c0 = blockIdx.x * 64, r0 = blockIdx.y * 64;
    int tx = threadIdx.x & 15, ty = threadIdx.x >> 4;
    const float* src = W + (size_t)e * R * C;
    #pragma unroll
    for (int j = 0; j < 4; ++j) {
        int r = ty + 16 * j;
        float4 v = *(const float4*)(src + (size_t)(r0 + r) * C + c0 + tx * 4);
        *(float4*)&tile[r][tx * 4] = v;
    }
    __syncthreads();
    unsigned short* dst = WT + (size_t)e * C * R;
    int sx = threadIdx.x & 7, sy = threadIdx.x >> 3;
    #pragma unroll
    for (int j = 0; j < 2; ++j) {
        int c = sy + 32 * j;
        u16x8 o;
        #pragma unroll
        for (int k = 0; k < 8; ++k) o[k] = f2bf(tile[sx * 8 + k][c]);
        *(u16x8*)(dst + (size_t)(c0 + c) * R + r0 + sx * 8) = o;
    }
}

// ---- one K-step compute: per-wave 64x64 C, K=32 (single kk), 16 MFMA ----
#define GEMM_COMPUTE(Abuf, Bbuf) do {                                                      \
    bf16x8 af[4], bf[4];                                                                   \
    _Pragma("unroll")                                                                      \
    for (int m_ = 0; m_ < 4; ++m_)                                                         \
        af[m_] = lds_frag32((Abuf), wm + m_ * 16 + (lane & 15), lane >> 4);                \
    _Pragma("unroll")                                                                      \
    for (int n_ = 0; n_ < 4; ++n_)                                                         \
        bf[n_] = lds_frag32((Bbuf), wn + n_ * 16 + (lane & 15), lane >> 4);                \
    _Pragma("unroll")                                                                      \
    for (int m_ = 0; m_ < 4; ++m_)                                                         \
        _Pragma("unroll")                                                                  \
        for (int n_ = 0; n_ < 4; ++n_)                                                     \
            acc[m_][n_] = __builtin_amdgcn_mfma_f32_16x16x32_bf16(af[m_], bf[n_],          \
                                                                  acc[m_][n_], 0, 0, 0);  \
} while (0)

// Pipelined dbuf loop, counted vmcnt(2) (2 loads/thread in flight). R7-proven sync.
#define GEMM_LOOP(NT, STAGE) do {                                                          \
    STAGE(0, 0);                                                                           \
    for (int t = 0; t < (NT); ++t) {                                                       \
        int cbuf = t & 1;                                                                  \
        if (t + 1 < (NT)) {                                                                \
            STAGE((t + 1) * BK, cbuf ^ 1);                                                 \
            asm volatile("s_waitcnt vmcnt(2)" ::: "memory");                               \
        } else {                                                                           \
            asm volatile("s_waitcnt vmcnt(0)" ::: "memory");                               \
        }                                                                                  \
        __builtin_amdgcn_s_barrier();                                                      \
        __builtin_amdgcn_s_setprio(1);                                                     \
        GEMM_COMPUTE(As[cbuf], Bs[cbuf]);                                                  \
        __builtin_amdgcn_s_setprio(0);                                                     \
        asm volatile("s_waitcnt lgkmcnt(0)" ::: "memory");                                 \
        __builtin_amdgcn_s_barrier();                                                      \
    }                                                                                      \
} while (0)

// ---------------- FC1: h = gelu(x @ W1 + b1); persistent blocks, XCD work loop ----------------
__global__ __launch_bounds__(1024, 4) void fc1_kernel(
    const unsigned short* __restrict__ xb,    // [T][D] bf16
    const unsigned short* __restrict__ W1T,   // [E][F][D] bf16
    const float* __restrict__ b1,             // [E][F]
    const int* __restrict__ perm,
    const int* __restrict__ meta,
    unsigned short* __restrict__ h)           // [NPAIR][F] bf16
{
    __shared__ __align__(16) unsigned short As[2][BM * BK];   // 2 x 16 KB
    __shared__ __align__(16) unsigned short Bs[2][BN * BK];   // 2 x 16 KB

    int nt = meta[0];
    int total = nt * 16;                      // items: tile-major x 16 n0-blocks
    int ipx = (total + 7) >> 3;               // items per XCD
    int xcd = blockIdx.x & 7;
    int slot = blockIdx.x >> 3;               // 0..31
    int lim = (xcd + 1) * ipx; if (lim > total) lim = total;

    int tid = threadIdx.x, lane = tid & 63, wv = tid >> 6;    // 16 waves
    int wm = (wv >> 2) * 64, wn = (wv & 3) * 64;
    // staging lane geometry: wave wv covers rows [wv*16, wv*16+16), lane -> row/slot
    int row_st = wv * 16 + (lane >> 2);
    int slot_st = lane & 3;
    int csw = ((slot_st ^ swz4(row_st)) * 8);                 // pre-swizzled col (shorts)
    unsigned short* ldsA = &As[0][0] + wv * 512 + lane * 8;   // +b*BM*BK for buffer b
    unsigned short* ldsB = &Bs[0][0] + wv * 512 + lane * 8;

    for (int item = xcd * ipx + slot; item < lim; item += 32) {
        int tile = item >> 4;
        int n0 = (item & 15) * BN;
        int e    = meta[32 + tile];
        int rs   = meta[160 + tile];
        int rend = meta[288 + tile];

        int pos = rs + row_st; if (pos >= NPAIR) pos = NPAIR - 1;
        const unsigned short* aptr = xb + (size_t)(perm[pos] >> 1) * D_DIM + csw;
        const unsigned short* bptr = W1T + ((size_t)e * F_DIM + n0 + row_st) * D_DIM + csw;

        f32x4 acc[4][4] = {};

#define STAGE1(k0, b) do {                                         \
    load_lds16(aptr + (k0), ldsA + (b) * (BM * BK));               \
    load_lds16(bptr + (k0), ldsB + (b) * (BN * BK));               \
} while (0)

        GEMM_LOOP(D_DIM / BK, STAGE1);   // 32 steps
#undef STAGE1

        #pragma unroll
        for (int m = 0; m < 4; ++m) {
            #pragma unroll
            for (int j = 0; j < 4; ++j) {
                int r = wm + m * 16 + (lane >> 4) * 4 + j;
                int p = rs + r;
                if (p >= rend) continue;
                #pragma unroll
                for (int n = 0; n < 4; ++n) {
                    int col = n0 + wn + n * 16 + (lane & 15);
                    float v = acc[m][n][j] + b1[e * F_DIM + col];
                    v = 0.5f * v * (1.f + erff(v * 0.70710678118654752f));  // exact GELU
                    h[(size_t)p * F_DIM + col] = f2bf(v);
                }
            }
        }
        __builtin_amdgcn_s_barrier();   // epilogue reads none of LDS, but keep items aligned
    }
}

// ---------------- FC2: out += w * (h @ W2 + b2); splitK=2, persistent blocks ----------------
__global__ __launch_bounds__(1024, 4) void fc2_kernel(
    const unsigned short* __restrict__ h,     // [NPAIR][F] bf16 (grouped rows contiguous)
    const unsigned short* __restrict__ W2T,   // [E][D][F] bf16
    const float* __restrict__ b2,             // [E][D]
    const int* __restrict__ perm,
    const float* __restrict__ tk_w,
    const int* __restrict__ meta,
    float* __restrict__ out)                  // [T][D] fp32 (zeroed)
{
    __shared__ __align__(16) unsigned short As[2][BM * BK];
    __shared__ __align__(16) unsigned short Bs[2][BN * BK];

    int nt = meta[0];
    int total = nt * 8;                       // tile-major x (4 n0 x 2 ks)
    int ipx = (total + 7) >> 3;
    int xcd = blockIdx.x & 7;
    int slot = blockIdx.x >> 3;
    int lim = (xcd + 1) * ipx; if (lim > total) lim = total;

    int tid = threadIdx.x, lane = tid & 63, wv = tid >> 6;
    int wm = (wv >> 2) * 64, wn = (wv & 3) * 64;
    int row_st = wv * 16 + (lane >> 2);
    int slot_st = lane & 3;
    int csw = ((slot_st ^ swz4(row_st)) * 8);
    unsigned short* ldsA = &As[0][0] + wv * 512 + lane * 8;
    unsigned short* ldsB = &Bs[0][0] + wv * 512 + lane * 8;

    for (int item = xcd * ipx + slot; item < lim; item += 32) {
        int tile = item >> 3;
        int rem  = item & 7;
        int n0 = (rem >> 1) * BN;
        int ks = rem & 1;
        int kbeg = ks * (F_DIM / 2);
        int e    = meta[32 + tile];
        int rs   = meta[160 + tile];
        int rend = meta[288 + tile];

        int pos = rs + row_st; if (pos >= NPAIR) pos = NPAIR - 1;
        const unsigned short* aptr = h + (size_t)pos * F_DIM + kbeg + csw;
        const unsigned short* bptr = W2T + ((size_t)e * D_DIM + n0 + row_st) * F_DIM + kbeg + csw;

        f32x4 acc[4][4] = {};

#define STAGE2(k0, b) do {                                         \
    load_lds16(aptr + (k0), ldsA + (b) * (BM * BK));               \
    load_lds16(bptr + (k0), ldsB + (b) * (BN * BK));               \
} while (0)

        GEMM_LOOP((F_DIM / 2) / BK, STAGE2);   // 64 steps
#undef STAGE2

        #pragma unroll
        for (int m = 0; m < 4; ++m) {
            #pragma unroll
            for (int j = 0; j < 4; ++j) {
                int r = wm + m * 16 + (lane >> 4) * 4 + j;
                int p = rs + r;
                if (p >= rend) continue;
                int pr = perm[p];
                int t2 = pr >> 1;
                float w = tk_w[pr];
                #pragma unroll
                for (int n = 0; n < 4; ++n) {
                    int col = n0 + wn + n * 16 + (lane & 15);
                    float base = (ks == 0) ? b2[e * D_DIM + col] : 0.f;
                    float v = (acc[m][n][j] + base) * w;
                    atomicAdd(&out[(size_t)t2 * D_DIM + col], v);
                }
            }
        }
        __builtin_amdgcn_s_barrier();
    }
}

extern "C" void kernel_launch(void* const* d_in, const int* in_sizes, int n_in,
                              void* d_out, int out_size, void* d_ws, size_t ws_size,
                              hipStream_t stream)
{
    const float* x     = (const float*)d_in[0];
    const float* noise = (const float*)d_in[1];
    const float* Wg    = (const float*)d_in[2];
    const float* bg    = (const float*)d_in[3];
    const float* Wn    = (const float*)d_in[4];
    const float* bn    = (const float*)d_in[5];
    const float* W1    = (const float*)d_in[6];
    const float* b1    = (const float*)d_in[7];
    const float* W2    = (const float*)d_in[8];
    const float* b2    = (const float*)d_in[9];

    float* out       = (float*)d_out;
    float* out_noisy = out + (size_t)T_TOK * D_DIM;
    float* out_gate  = out_noisy + (size_t)T_TOK * E_NUM;

    char* ws = (char*)d_ws;
    int*   tk_idx = (int*)ws;
    float* tk_w   = (float*)(ws + 32768);
    int*   perm   = (int*)(ws + 65536);
    int*   meta   = (int*)(ws + 98304);
    size_t off = 131072;
    unsigned short* xb   = (unsigned short*)(ws + off); off += (size_t)T_TOK * D_DIM * 2;
    unsigned short* W1T  = (unsigned short*)(ws + off); off += (size_t)E_NUM * F_DIM * D_DIM * 2;
    unsigned short* W2T  = (unsigned short*)(ws + off); off += (size_t)E_NUM * D_DIM * F_DIM * 2;
    unsigned short* hbuf = (unsigned short*)(ws + off); off += (size_t)NPAIR * F_DIM * 2;

    hipMemsetAsync(d_out, 0, (size_t)out_size * sizeof(float), stream);

    router_convert_kernel<<<T_TOK / 4, 256, 0, stream>>>(x, noise, Wg, bg, Wn, bn,
                                                         out_noisy, out_gate, tk_idx, tk_w, xb);
    scan_scatter_kernel<<<1, 256, 0, stream>>>(tk_idx, perm, meta);
    // W2T early (its L3 footprint precedes fc1's streaming); W1T right before fc1.
    transpose_kernel<<<dim3(D_DIM / 64, F_DIM / 64, E_NUM), 256, 0, stream>>>(W2, W2T, F_DIM, D_DIM);
    transpose_kernel<<<dim3(F_DIM / 64, D_DIM / 64, E_NUM), 256, 0, stream>>>(W1, W1T, D_DIM, F_DIM);

    fc1_kernel<<<256, 1024, 0, stream>>>(xb, W1T, b1, perm, meta, hbuf);
    fc2_kernel<<<256, 1024, 0, stream>>>(hbuf, W2T, b2, perm, tk_w, meta, out);
}